// Round 1
// baseline (7738.698 us; speedup 1.0000x reference)
//
#include <hip/hip_runtime.h>
#include <math.h>

#define NB 1024
#define ND 512
#define ND2 1024
#define NSTEPS 8
#define NSTACK 16
#define NK 1024
#define NV 32000
#define FEPS 1e-6f

// ---------------- block reduction helpers (blockDim == 256) ----------------
__device__ __forceinline__ float blk_sum(float v, float* red) {
    int t = threadIdx.x;
    red[t] = v; __syncthreads();
    for (int s = 128; s > 0; s >>= 1) {
        if (t < s) red[t] += red[t + s];
        __syncthreads();
    }
    float r = red[0]; __syncthreads();
    return r;
}

__device__ __forceinline__ float blk_max(float v, float* red) {
    int t = threadIdx.x;
    red[t] = v; __syncthreads();
    for (int s = 128; s > 0; s >>= 1) {
        if (t < s) red[t] = fmaxf(red[t], red[t + s]);
        __syncthreads();
    }
    float r = red[0]; __syncthreads();
    return r;
}

// ---------------- init ----------------
__global__ __launch_bounds__(256)
void k_init(float* ptrb, float* remainb, float* scal) {
    int i = blockIdx.x * 256 + threadIdx.x;
    if (i < NB) {
        remainb[i] = 1.f;
        for (int s = 0; s < NSTACK; ++s) ptrb[i * NSTACK + s] = (s == 0) ? 1.f : 0.f;
    }
    if (i < 8) scal[i] = 0.f;
}

__global__ __launch_bounds__(256)
void k_embed(const int* __restrict__ ids, const float* __restrict__ mag,
             const float* __restrict__ ph, float* __restrict__ zr, float* __restrict__ zi) {
    int b = blockIdx.x;
    int id = ids[b];
    for (int d = threadIdx.x; d < ND; d += 256) {
        float m = mag[(size_t)id * ND + d];
        float p = ph[(size_t)id * ND + d];
        zr[b * ND + d] = m * cosf(p);
        zi[b * ND + d] = m * sinf(p);
    }
}

__global__ __launch_bounds__(256)
void k_cbnorm(const float* __restrict__ cb, float* __restrict__ cbn) {
    __shared__ float red[256];
    int k = blockIdx.x;
    float s = 0.f;
    for (int c = threadIdx.x; c < ND2; c += 256) {
        float v = cb[(size_t)k * ND2 + c];
        s += v * v;
    }
    float tot = blk_sum(s, red);
    if (threadIdx.x == 0) cbn[k] = tot;
}

// ---------------- complex linear: Or = Ar*Wr^T - Ai*Wi^T ; Oi = Ai*Wr^T + Ar*Wi^T
// A: M x Kd row-major, W: N x Kd row-major, O: M x N row-major. M,N,Kd % 64/16 == 0.
__global__ __launch_bounds__(256)
void k_clin(const float* __restrict__ Ar, const float* __restrict__ Ai,
            const float* __restrict__ Wr, const float* __restrict__ Wi,
            float* __restrict__ Or, float* __restrict__ Oi,
            int M, int N, int Kd) {
    __shared__ float sAr[64][17], sAi[64][17], sWr[64][17], sWi[64][17];
    const int tid = threadIdx.x;
    const int tx = tid & 15, ty = tid >> 4;
    const int m0 = blockIdx.y * 64, n0 = blockIdx.x * 64;
    const int r = tid >> 2, kq = (tid & 3) * 4;
    float accR[4][4] = {{0}}, accI[4][4] = {{0}};
    for (int k0 = 0; k0 < Kd; k0 += 16) {
        float4 ar4 = *(const float4*)&Ar[(size_t)(m0 + r) * Kd + k0 + kq];
        float4 ai4 = *(const float4*)&Ai[(size_t)(m0 + r) * Kd + k0 + kq];
        float4 wr4 = *(const float4*)&Wr[(size_t)(n0 + r) * Kd + k0 + kq];
        float4 wi4 = *(const float4*)&Wi[(size_t)(n0 + r) * Kd + k0 + kq];
        sAr[r][kq] = ar4.x; sAr[r][kq+1] = ar4.y; sAr[r][kq+2] = ar4.z; sAr[r][kq+3] = ar4.w;
        sAi[r][kq] = ai4.x; sAi[r][kq+1] = ai4.y; sAi[r][kq+2] = ai4.z; sAi[r][kq+3] = ai4.w;
        sWr[r][kq] = wr4.x; sWr[r][kq+1] = wr4.y; sWr[r][kq+2] = wr4.z; sWr[r][kq+3] = wr4.w;
        sWi[r][kq] = wi4.x; sWi[r][kq+1] = wi4.y; sWi[r][kq+2] = wi4.z; sWi[r][kq+3] = wi4.w;
        __syncthreads();
        #pragma unroll
        for (int kk = 0; kk < 16; ++kk) {
            float arv[4], aiv[4], wrv[4], wiv[4];
            #pragma unroll
            for (int i = 0; i < 4; ++i) { arv[i] = sAr[ty*4+i][kk]; aiv[i] = sAi[ty*4+i][kk]; }
            #pragma unroll
            for (int j = 0; j < 4; ++j) { wrv[j] = sWr[tx*4+j][kk]; wiv[j] = sWi[tx*4+j][kk]; }
            #pragma unroll
            for (int i = 0; i < 4; ++i)
                #pragma unroll
                for (int j = 0; j < 4; ++j) {
                    accR[i][j] += arv[i]*wrv[j] - aiv[i]*wiv[j];
                    accI[i][j] += aiv[i]*wrv[j] + arv[i]*wiv[j];
                }
        }
        __syncthreads();
    }
    #pragma unroll
    for (int i = 0; i < 4; ++i)
        #pragma unroll
        for (int j = 0; j < 4; ++j) {
            size_t off = (size_t)(m0 + ty*4 + i) * N + n0 + tx*4 + j;
            Or[off] = accR[i][j];
            Oi[off] = accI[i][j];
        }
}

// ---------------- score: S[m,n] = scale * sum_d (Qr[m,d]Kr[n,d] + Qi[m,d]Ki[n,d])
__global__ __launch_bounds__(256)
void k_score(const float* __restrict__ Qr, const float* __restrict__ Qi,
             const float* __restrict__ Kr, const float* __restrict__ Ki,
             float* __restrict__ S, int M, int N, int Kd, float scale) {
    __shared__ float sQr[64][17], sQi[64][17], sKr[64][17], sKi[64][17];
    const int tid = threadIdx.x;
    const int tx = tid & 15, ty = tid >> 4;
    const int m0 = blockIdx.y * 64, n0 = blockIdx.x * 64;
    const int r = tid >> 2, kq = (tid & 3) * 4;
    float acc[4][4] = {{0}};
    for (int k0 = 0; k0 < Kd; k0 += 16) {
        float4 a = *(const float4*)&Qr[(size_t)(m0 + r) * Kd + k0 + kq];
        float4 b = *(const float4*)&Qi[(size_t)(m0 + r) * Kd + k0 + kq];
        float4 c = *(const float4*)&Kr[(size_t)(n0 + r) * Kd + k0 + kq];
        float4 d = *(const float4*)&Ki[(size_t)(n0 + r) * Kd + k0 + kq];
        sQr[r][kq] = a.x; sQr[r][kq+1] = a.y; sQr[r][kq+2] = a.z; sQr[r][kq+3] = a.w;
        sQi[r][kq] = b.x; sQi[r][kq+1] = b.y; sQi[r][kq+2] = b.z; sQi[r][kq+3] = b.w;
        sKr[r][kq] = c.x; sKr[r][kq+1] = c.y; sKr[r][kq+2] = c.z; sKr[r][kq+3] = c.w;
        sKi[r][kq] = d.x; sKi[r][kq+1] = d.y; sKi[r][kq+2] = d.z; sKi[r][kq+3] = d.w;
        __syncthreads();
        #pragma unroll
        for (int kk = 0; kk < 16; ++kk) {
            float qr_[4], qi_[4], kr_[4], ki_[4];
            #pragma unroll
            for (int i = 0; i < 4; ++i) { qr_[i] = sQr[ty*4+i][kk]; qi_[i] = sQi[ty*4+i][kk]; }
            #pragma unroll
            for (int j = 0; j < 4; ++j) { kr_[j] = sKr[tx*4+j][kk]; ki_[j] = sKi[tx*4+j][kk]; }
            #pragma unroll
            for (int i = 0; i < 4; ++i)
                #pragma unroll
                for (int j = 0; j < 4; ++j)
                    acc[i][j] += qr_[i]*kr_[j] + qi_[i]*ki_[j];
        }
        __syncthreads();
    }
    #pragma unroll
    for (int i = 0; i < 4; ++i)
        #pragma unroll
        for (int j = 0; j < 4; ++j)
            S[(size_t)(m0 + ty*4 + i) * N + n0 + tx*4 + j] = acc[i][j] * scale;
}

// ---------------- generic NT gemm: O[m,n] = sum_k A[m,k]*W[n,k] (+bias[n])
__global__ __launch_bounds__(256)
void k_gemm_nt(const float* __restrict__ A, const float* __restrict__ W,
               float* __restrict__ O, int M, int N, int Kd,
               const float* __restrict__ bias) {
    __shared__ float sA[64][17], sW[64][17];
    const int tid = threadIdx.x;
    const int tx = tid & 15, ty = tid >> 4;
    const int m0 = blockIdx.y * 64, n0 = blockIdx.x * 64;
    const int r = tid >> 2, kq = (tid & 3) * 4;
    float acc[4][4] = {{0}};
    for (int k0 = 0; k0 < Kd; k0 += 16) {
        float4 a = *(const float4*)&A[(size_t)(m0 + r) * Kd + k0 + kq];
        float4 w = *(const float4*)&W[(size_t)(n0 + r) * Kd + k0 + kq];
        sA[r][kq] = a.x; sA[r][kq+1] = a.y; sA[r][kq+2] = a.z; sA[r][kq+3] = a.w;
        sW[r][kq] = w.x; sW[r][kq+1] = w.y; sW[r][kq+2] = w.z; sW[r][kq+3] = w.w;
        __syncthreads();
        #pragma unroll
        for (int kk = 0; kk < 16; ++kk) {
            float av[4], wv[4];
            #pragma unroll
            for (int i = 0; i < 4; ++i) av[i] = sA[ty*4+i][kk];
            #pragma unroll
            for (int j = 0; j < 4; ++j) wv[j] = sW[tx*4+j][kk];
            #pragma unroll
            for (int i = 0; i < 4; ++i)
                #pragma unroll
                for (int j = 0; j < 4; ++j)
                    acc[i][j] += av[i] * wv[j];
        }
        __syncthreads();
    }
    #pragma unroll
    for (int i = 0; i < 4; ++i)
        #pragma unroll
        for (int j = 0; j < 4; ++j) {
            float bval = bias ? bias[n0 + tx*4 + j] : 0.f;
            O[(size_t)(m0 + ty*4 + i) * N + n0 + tx*4 + j] = acc[i][j] + bval;
        }
}

// ---------------- NN dual gemm: O[:, 0:N] = A@V1, O[:, N:2N] = A@V2 (ldc = 2N)
__global__ __launch_bounds__(256)
void k_nn_dual(const float* __restrict__ A, const float* __restrict__ V1,
               const float* __restrict__ V2, float* __restrict__ O,
               int M, int N, int Kd) {
    __shared__ float sA[64][17], sV1[16][64], sV2[16][64];
    const int tid = threadIdx.x;
    const int tx = tid & 15, ty = tid >> 4;
    const int m0 = blockIdx.y * 64, n0 = blockIdx.x * 64;
    const int r = tid >> 2, kq = (tid & 3) * 4;
    const int vr_ = tid >> 4, vc = (tid & 15) * 4;
    const int ldc = 2 * N;
    float acc1[4][4] = {{0}}, acc2[4][4] = {{0}};
    for (int k0 = 0; k0 < Kd; k0 += 16) {
        float4 a = *(const float4*)&A[(size_t)(m0 + r) * Kd + k0 + kq];
        float4 v1 = *(const float4*)&V1[(size_t)(k0 + vr_) * N + n0 + vc];
        float4 v2 = *(const float4*)&V2[(size_t)(k0 + vr_) * N + n0 + vc];
        sA[r][kq] = a.x; sA[r][kq+1] = a.y; sA[r][kq+2] = a.z; sA[r][kq+3] = a.w;
        sV1[vr_][vc] = v1.x; sV1[vr_][vc+1] = v1.y; sV1[vr_][vc+2] = v1.z; sV1[vr_][vc+3] = v1.w;
        sV2[vr_][vc] = v2.x; sV2[vr_][vc+1] = v2.y; sV2[vr_][vc+2] = v2.z; sV2[vr_][vc+3] = v2.w;
        __syncthreads();
        #pragma unroll
        for (int kk = 0; kk < 16; ++kk) {
            float av[4], v1v[4], v2v[4];
            #pragma unroll
            for (int i = 0; i < 4; ++i) av[i] = sA[ty*4+i][kk];
            #pragma unroll
            for (int j = 0; j < 4; ++j) { v1v[j] = sV1[kk][tx*4+j]; v2v[j] = sV2[kk][tx*4+j]; }
            #pragma unroll
            for (int i = 0; i < 4; ++i)
                #pragma unroll
                for (int j = 0; j < 4; ++j) {
                    acc1[i][j] += av[i] * v1v[j];
                    acc2[i][j] += av[i] * v2v[j];
                }
        }
        __syncthreads();
    }
    #pragma unroll
    for (int i = 0; i < 4; ++i)
        #pragma unroll
        for (int j = 0; j < 4; ++j) {
            size_t row = (size_t)(m0 + ty*4 + i);
            O[row * ldc + n0 + tx*4 + j]     = acc1[i][j];
            O[row * ldc + N + n0 + tx*4 + j] = acc2[i][j];
        }
}

// ---------------- cnorm + modrelu, in place on pr, pi (rows of ND)
__global__ __launch_bounds__(256)
void k_cnorm(float* __restrict__ pr, float* __restrict__ pi,
             const float* __restrict__ scale, const float* __restrict__ shift,
             const float* __restrict__ mbias) {
    __shared__ float red[256];
    int b = blockIdx.x, t = threadIdx.x;
    float prv[2], piv[2], hv[2];
    float lsum = 0.f;
    #pragma unroll
    for (int l = 0; l < 2; ++l) {
        int d = t + l * 256;
        float a = pr[(size_t)b * ND + d], c = pi[(size_t)b * ND + d];
        prv[l] = a; piv[l] = c;
        float h = sqrtf(a * a + c * c);
        hv[l] = h;
        lsum += h + FEPS;
    }
    float mean = blk_sum(lsum, red) * (1.f / ND);
    float lvar = 0.f;
    #pragma unroll
    for (int l = 0; l < 2; ++l) {
        float dv = (hv[l] + FEPS) - mean;
        lvar += dv * dv;
    }
    float var = blk_sum(lvar, red) * (1.f / (ND - 1));
    float istd = 1.f / sqrtf(var + FEPS);
    #pragma unroll
    for (int l = 0; l < 2; ++l) {
        int d = t + l * 256;
        float nm = ((hv[l] + FEPS) - mean) * istd * scale[d] + shift[d];
        float cc, ss;
        if (hv[l] > 0.f) { cc = prv[l] / hv[l]; ss = piv[l] / hv[l]; }
        else             { cc = 1.f; ss = 0.f; }
        float xr = nm * cc, xi = nm * ss;
        float n = sqrtf(xr * xr + xi * xi) + FEPS;
        float aarg = n + mbias[d];
        float sg = (aarg > 0.f ? aarg : 0.f) / n;
        pr[(size_t)b * ND + d] = xr * sg;
        pi[(size_t)b * ND + d] = xi * sg;
    }
}

// ---------------- row softmax over N=1024
__global__ __launch_bounds__(256)
void k_softmax(float* __restrict__ S) {
    __shared__ float red[256];
    int row = blockIdx.x, t = threadIdx.x;
    float v[4];
    float lm = -INFINITY;
    #pragma unroll
    for (int l = 0; l < 4; ++l) {
        v[l] = S[(size_t)row * NB + t + l * 256];
        lm = fmaxf(lm, v[l]);
    }
    float mx = blk_max(lm, red);
    float ls = 0.f;
    #pragma unroll
    for (int l = 0; l < 4; ++l) { v[l] = expf(v[l] - mx); ls += v[l]; }
    float tot = blk_sum(ls, red);
    float inv = 1.f / tot;
    #pragma unroll
    for (int l = 0; l < 4; ++l) S[(size_t)row * NB + t + l * 256] = v[l] * inv;
}

// ---------------- halt/ctrl/stack/read/cf  (one block per batch row)
__global__ __launch_bounds__(256)
void k_stack(const float* __restrict__ zf, const float* __restrict__ hW,
             const float* __restrict__ hB, const float* __restrict__ cW,
             const float* __restrict__ cB, float* __restrict__ ptrb,
             float* __restrict__ memb, float* __restrict__ haltb,
             float* __restrict__ cf) {
    __shared__ float zfs[ND2];
    __shared__ float red[256];
    __shared__ float pt[NSTACK], npv[NSTACK], wmv[NSTACK];
    __shared__ float snorm;
    int b = blockIdx.x, t = threadIdx.x;
    for (int c = t; c < ND2; c += 256) zfs[c] = zf[(size_t)b * ND2 + c];
    __syncthreads();
    float dh = 0, d0 = 0, d1 = 0, d2 = 0;
    for (int c = t; c < ND2; c += 256) {
        float z = zfs[c];
        dh += z * hW[c];
        d0 += z * cW[c];
        d1 += z * cW[ND2 + c];
        d2 += z * cW[2 * ND2 + c];
    }
    dh = blk_sum(dh, red);
    d0 = blk_sum(d0, red);
    d1 = blk_sum(d1, red);
    d2 = blk_sum(d2, red);
    float h = 1.f / (1.f + expf(-(dh + hB[0])));
    float l0 = d0 + cB[0], l1 = d1 + cB[1], l2 = d2 + cB[2];
    float mx = fmaxf(l0, fmaxf(l1, l2));
    float e0 = expf(l0 - mx), e1 = expf(l1 - mx), e2 = expf(l2 - mx);
    float es = e0 + e1 + e2;
    float push = e0 / es, pop = e1 / es, noop = e2 / es;
    if (t < NSTACK) pt[t] = ptrb[b * NSTACK + t];
    __syncthreads();
    if (t < NSTACK) {
        float up = pt[(t + NSTACK - 1) & 15];
        float dn = pt[(t + 1) & 15];
        npv[t] = push * up + pop * dn + noop * pt[t];
        wmv[t] = push * up;
    }
    __syncthreads();
    if (t == 0) {
        float s = 0.f;
        for (int j = 0; j < NSTACK; ++j) s += npv[j];
        snorm = 1.f / (s + FEPS);
    }
    __syncthreads();
    if (t < NSTACK) {
        npv[t] *= snorm;
        ptrb[b * NSTACK + t] = npv[t];
    }
    __syncthreads();
    for (int c = t; c < ND2; c += 256) {
        float z = zfs[c];
        float rd = 0.f;
        #pragma unroll
        for (int s = 0; s < NSTACK; ++s) {
            size_t off = ((size_t)b * NSTACK + s) * ND2 + c;
            float m = memb[off];
            m = wmv[s] * z + m * (1.f - wmv[s]);
            memb[off] = m;
            rd += m * npv[s];
        }
        cf[(size_t)b * ND2 + c] = z + rd;
    }
    if (t == 0) haltb[b] = h;
}

// ---------------- VQ argmin + losses + state update (one block per batch row)
__global__ __launch_bounds__(256)
void k_vqstep(const float* __restrict__ G, const float* __restrict__ cf,
              const float* __restrict__ cb, const float* __restrict__ cbn,
              const float* __restrict__ adj, const float* __restrict__ haltb,
              float* __restrict__ remainb, float* __restrict__ zr,
              float* __restrict__ zi, float* __restrict__ zw,
              int* __restrict__ prev, float* __restrict__ scal,
              int step, int islast) {
    __shared__ float sval[256];
    __shared__ int sidx[256];
    __shared__ float red[256];
    int b = blockIdx.x, t = threadIdx.x;
    float bv = INFINITY; int bi = NK;
    for (int k = t; k < NK; k += 256) {
        float v = cbn[k] - 2.f * G[(size_t)b * NK + k];
        if (v < bv) { bv = v; bi = k; }
    }
    sval[t] = bv; sidx[t] = bi;
    __syncthreads();
    for (int s = 128; s > 0; s >>= 1) {
        if (t < s) {
            float ov = sval[t + s]; int oi = sidx[t + s];
            if (ov < sval[t] || (ov == sval[t] && oi < sidx[t])) { sval[t] = ov; sidx[t] = oi; }
        }
        __syncthreads();
    }
    int sym = sidx[0];
    // vq loss: direct sum of squared diffs
    float sd = 0.f;
    for (int c = t; c < ND2; c += 256) {
        float dd = cb[(size_t)sym * ND2 + c] - cf[(size_t)b * ND2 + c];
        sd += dd * dd;
    }
    float sdt = blk_sum(sd, red);
    // eth: logsumexp(adjacency[prev]) - adjacency[prev][sym]
    float contrib = 0.f;
    if (step > 0) {
        int pv = prev[b];
        float lm = -INFINITY;
        for (int c = t; c < NK; c += 256) lm = fmaxf(lm, adj[(size_t)pv * NK + c]);
        float mxa = blk_max(lm, red);
        float le = 0.f;
        for (int c = t; c < NK; c += 256) le += expf(adj[(size_t)pv * NK + c] - mxa);
        float se = blk_sum(le, red);
        contrib = (mxa + logf(se)) - adj[(size_t)pv * NK + sym];
    }
    float hb = haltb[b];
    float rm = remainb[b];
    float w = islast ? rm : hb * rm;
    for (int c = t; c < ND2; c += 256)
        zw[(size_t)b * ND2 + c] += w * cb[(size_t)sym * ND2 + c];
    for (int d = t; d < ND; d += 256) {
        zr[(size_t)b * ND + d] = cb[(size_t)sym * ND2 + d];
        zi[(size_t)b * ND + d] = cb[(size_t)sym * ND2 + ND + d];
    }
    if (t == 0) {
        float nrm = rm * (1.f - hb);
        remainb[b] = nrm;
        atomicAdd(&scal[0], sdt);
        if (step > 0) atomicAdd(&scal[1], contrib);
        atomicAdd(&scal[2], nrm);
        prev[b] = sym;
    }
}

__global__ void k_aux(const float* __restrict__ scal, float* __restrict__ out) {
    out[0] = 1.25f * scal[0] / (1024.f * 1024.f)
           + 0.005f * (scal[1] / 1024.f)
           + 0.0001f * (scal[2] / 1024.f);
}

// ---------------- launch ----------------
extern "C" void kernel_launch(void* const* d_in, const int* in_sizes, int n_in,
                              void* d_out, int out_size, void* d_ws, size_t ws_size,
                              hipStream_t stream) {
    const int*   input_ids  = (const int*)  d_in[0];
    const float* emb_mag    = (const float*)d_in[1];
    const float* emb_phase  = (const float*)d_in[2];
    const float* lin_r      = (const float*)d_in[3];
    const float* lin_i      = (const float*)d_in[4];
    const float* norm_scale = (const float*)d_in[5];
    const float* norm_shift = (const float*)d_in[6];
    const float* mod_bias   = (const float*)d_in[7];
    const float* halt_W     = (const float*)d_in[8];
    const float* halt_b     = (const float*)d_in[9];
    const float* ctrl_W     = (const float*)d_in[10];
    const float* ctrl_b     = (const float*)d_in[11];
    const float* q_r        = (const float*)d_in[12];
    const float* q_i        = (const float*)d_in[13];
    const float* k_r        = (const float*)d_in[14];
    const float* k_i        = (const float*)d_in[15];
    const float* v_r        = (const float*)d_in[16];
    const float* v_i        = (const float*)d_in[17];
    const float* codebook   = (const float*)d_in[18];
    const float* adjacency  = (const float*)d_in[19];
    const float* dec_W      = (const float*)d_in[20];
    const float* dec_b      = (const float*)d_in[21];
    float* out = (float*)d_out;

    float* base = (float*)d_ws;
    size_t o = 0;
    auto alloc = [&](size_t n) { float* p = base + o; o += n; return p; };
    float* zr     = alloc((size_t)NB * ND);
    float* zi     = alloc((size_t)NB * ND);
    float* pr     = alloc((size_t)NB * ND);
    float* pi_    = alloc((size_t)NB * ND);
    float* qr     = alloc((size_t)NB * ND);
    float* qi     = alloc((size_t)NB * ND);
    float* kr     = alloc((size_t)NB * ND);
    float* ki     = alloc((size_t)NB * ND);
    float* vr     = alloc((size_t)NB * ND);
    float* vi     = alloc((size_t)NB * ND);
    float* S      = alloc((size_t)NB * NB);   // scores; reused as VQ dot matrix G
    float* zf     = alloc((size_t)NB * ND2);
    float* cf     = alloc((size_t)NB * ND2);
    float* memb   = alloc((size_t)NB * NSTACK * ND2);
    float* ptrb   = alloc((size_t)NB * NSTACK);
    float* haltb  = alloc(NB);
    float* remainb= alloc(NB);
    float* zw     = alloc((size_t)NB * ND2);
    float* cbn    = alloc(NK);
    int*   prev   = (int*)alloc(NB);
    float* scal   = alloc(8);

    hipMemsetAsync(memb, 0, (size_t)NB * NSTACK * ND2 * sizeof(float), stream);
    hipMemsetAsync(zw, 0, (size_t)NB * ND2 * sizeof(float), stream);
    k_init<<<4, 256, 0, stream>>>(ptrb, remainb, scal);
    k_embed<<<NB, 256, 0, stream>>>(input_ids, emb_mag, emb_phase, zr, zi);
    k_cbnorm<<<NK, 256, 0, stream>>>(codebook, cbn);

    const float att_scale = (float)(1.0 / sqrt((double)ND));
    for (int step = 0; step < NSTEPS; ++step) {
        k_clin<<<dim3(ND / 64, NB / 64), 256, 0, stream>>>(zr, zi, lin_r, lin_i, pr, pi_, NB, ND, ND);
        k_cnorm<<<NB, 256, 0, stream>>>(pr, pi_, norm_scale, norm_shift, mod_bias);
        k_clin<<<dim3(ND / 64, NB / 64), 256, 0, stream>>>(pr, pi_, q_r, q_i, qr, qi, NB, ND, ND);
        k_clin<<<dim3(ND / 64, NB / 64), 256, 0, stream>>>(pr, pi_, k_r, k_i, kr, ki, NB, ND, ND);
        k_clin<<<dim3(ND / 64, NB / 64), 256, 0, stream>>>(pr, pi_, v_r, v_i, vr, vi, NB, ND, ND);
        k_score<<<dim3(NB / 64, NB / 64), 256, 0, stream>>>(qr, qi, kr, ki, S, NB, NB, ND, att_scale);
        k_softmax<<<NB, 256, 0, stream>>>(S);
        k_nn_dual<<<dim3(ND / 64, NB / 64), 256, 0, stream>>>(S, vr, vi, zf, NB, ND, NB);
        k_stack<<<NB, 256, 0, stream>>>(zf, halt_W, halt_b, ctrl_W, ctrl_b, ptrb, memb, haltb, cf);
        k_gemm_nt<<<dim3(NK / 64, NB / 64), 256, 0, stream>>>(cf, codebook, S, NB, NK, ND2, nullptr);
        k_vqstep<<<NB, 256, 0, stream>>>(S, cf, codebook, cbn, adjacency, haltb, remainb,
                                         zr, zi, zw, prev, scal, step, step == NSTEPS - 1 ? 1 : 0);
    }
    k_gemm_nt<<<dim3(NV / 64, NB / 64), 256, 0, stream>>>(zw, dec_W, out, NB, NV, ND2, dec_b);
    k_aux<<<1, 1, 0, stream>>>(scal, out + (size_t)NB * NV);
}

// Round 2
// 2194.124 us; speedup vs baseline: 3.5270x; 3.5270x over previous
//
#include <hip/hip_runtime.h>
#include <math.h>

#define NB 1024
#define ND 512
#define ND2 1024
#define NSTEPS 8
#define NSTACK 16
#define NK 1024
#define NV 32000
#define FEPS 1e-6f

typedef _Float16 f16;
typedef f16 f16x8 __attribute__((ext_vector_type(8)));
typedef float f32x4 __attribute__((ext_vector_type(4)));

// ---------------- block reduction helpers (blockDim == 256) ----------------
__device__ __forceinline__ float blk_sum(float v, float* red) {
    int t = threadIdx.x;
    red[t] = v; __syncthreads();
    for (int s = 128; s > 0; s >>= 1) {
        if (t < s) red[t] += red[t + s];
        __syncthreads();
    }
    float r = red[0]; __syncthreads();
    return r;
}

__device__ __forceinline__ float blk_max(float v, float* red) {
    int t = threadIdx.x;
    red[t] = v; __syncthreads();
    for (int s = 128; s > 0; s >>= 1) {
        if (t < s) red[t] = fmaxf(red[t], red[t + s]);
        __syncthreads();
    }
    float r = red[0]; __syncthreads();
    return r;
}

__device__ __forceinline__ void split_write(float v, f16* oh, f16* ol, size_t idx) {
    f16 h = (f16)v;
    oh[idx] = h;
    ol[idx] = (f16)((v - (float)h) * 1024.f);
}

// ---------------- init ----------------
__global__ __launch_bounds__(256)
void k_init(float* ptrb, float* remainb, float* scal) {
    int i = blockIdx.x * 256 + threadIdx.x;
    if (i < NB) {
        remainb[i] = 1.f;
        for (int s = 0; s < NSTACK; ++s) ptrb[i * NSTACK + s] = (s == 0) ? 1.f : 0.f;
    }
    if (i < 8) scal[i] = 0.f;
}

__global__ __launch_bounds__(256)
void k_embed(const int* __restrict__ ids, const float* __restrict__ mag,
             const float* __restrict__ ph, f16* __restrict__ zh, f16* __restrict__ zl) {
    int b = blockIdx.x;
    int id = ids[b];
    for (int d = threadIdx.x; d < ND; d += 256) {
        float m = mag[(size_t)id * ND + d];
        float p = ph[(size_t)id * ND + d];
        split_write(m * cosf(p), zh, zl, (size_t)b * ND2 + d);
        split_write(m * sinf(p), zh, zl, (size_t)b * ND2 + ND + d);
    }
}

__global__ __launch_bounds__(256)
void k_cbnorm(const float* __restrict__ cb, float* __restrict__ cbn) {
    __shared__ float red[256];
    int k = blockIdx.x;
    float s = 0.f;
    for (int c = threadIdx.x; c < ND2; c += 256) {
        float v = cb[(size_t)k * ND2 + c];
        s += v * v;
    }
    float tot = blk_sum(s, red);
    if (threadIdx.x == 0) cbn[k] = tot;
}

// ---------------- weight builders ----------------
// W1c (1024x1024): rows 0..511 = [lin_r | -lin_i], rows 512..1023 = [lin_i | lin_r]
__global__ __launch_bounds__(256)
void k_buildW1(const float* __restrict__ lr, const float* __restrict__ li,
               f16* __restrict__ oh, f16* __restrict__ ol) {
    int idx = blockIdx.x * 256 + threadIdx.x;
    int n = idx >> 10, k = idx & 1023;
    float v;
    if (n < 512) v = (k < 512) ? lr[n * 512 + k] : -li[n * 512 + (k - 512)];
    else { int n2 = n - 512; v = (k < 512) ? li[n2 * 512 + k] : lr[n2 * 512 + (k - 512)]; }
    split_write(v, oh, ol, idx);
}

// Wqkv (3072x1024): groups q/k/v, each the complex-stack construction
__global__ __launch_bounds__(256)
void k_buildWqkv(const float* __restrict__ qr, const float* __restrict__ qi,
                 const float* __restrict__ kr, const float* __restrict__ ki,
                 const float* __restrict__ vr, const float* __restrict__ vi,
                 f16* __restrict__ oh, f16* __restrict__ ol) {
    int idx = blockIdx.x * 256 + threadIdx.x;
    int n = idx >> 10, k = idx & 1023;
    int g = n >> 10, n1 = n & 1023;
    const float* Wr = (g == 0) ? qr : (g == 1) ? kr : vr;
    const float* Wi = (g == 0) ? qi : (g == 1) ? ki : vi;
    float v;
    if (n1 < 512) v = (k < 512) ? Wr[n1 * 512 + k] : -Wi[n1 * 512 + (k - 512)];
    else { int n2 = n1 - 512; v = (k < 512) ? Wi[n2 * 512 + k] : Wr[n2 * 512 + (k - 512)]; }
    split_write(v, oh, ol, idx);
}

__global__ __launch_bounds__(256)
void k_splitcb(const float* __restrict__ in, f16* __restrict__ oh, f16* __restrict__ ol) {
    int idx = blockIdx.x * 256 + threadIdx.x;
    split_write(in[idx], oh, ol, idx);
}

__global__ __launch_bounds__(256)
void k_split_h(const float* __restrict__ in, f16* __restrict__ oh, size_t n) {
    size_t i = (size_t)blockIdx.x * 256 + threadIdx.x;
    size_t st = (size_t)gridDim.x * 256;
    for (; i < n; i += st) oh[i] = (f16)in[i];
}

// split a strided M x 1024 f32 region into packed hi/lo fp16
__global__ __launch_bounds__(256)
void k_split_str(const float* __restrict__ in, int ld,
                 f16* __restrict__ oh, f16* __restrict__ ol) {
    int b = blockIdx.x;
    for (int c = threadIdx.x; c < ND2; c += 256) {
        float v = in[(size_t)b * ld + c];
        split_write(v, oh, ol, (size_t)b * ND2 + c);
    }
}

// transpose-split: out[n][m] = in[m][n], in strided (ld), 1024x1024
__global__ __launch_bounds__(256)
void k_tsplit(const float* __restrict__ in, int ld,
              f16* __restrict__ oh, f16* __restrict__ ol) {
    __shared__ float tile[32][33];
    int bi = blockIdx.y, bj = blockIdx.x;
    int tx = threadIdx.x & 31, ty = threadIdx.x >> 5;
    for (int r = ty; r < 32; r += 8)
        tile[r][tx] = in[(size_t)(bi * 32 + r) * ld + bj * 32 + tx];
    __syncthreads();
    for (int r = ty; r < 32; r += 8) {
        float v = tile[tx][r];
        split_write(v, oh, ol, (size_t)(bj * 32 + r) * ND2 + bi * 32 + tx);
    }
}

// ---------------- fp16(x2-split) MFMA NT GEMM ----------------
// C[M,N] = alpha * (A .* B^T) (+bias), A*: MxK f16 row-major, B*: NxK f16 row-major.
// value = hi + lo/1024. SPLIT=1: 3-product compensated; SPLIT=0: hi only.
// Tile 64x64, BK=32, 256 threads = 4 waves (2x2), wave tile 32x32.
#define LDP 72   // padded LDS row stride (halfs): 144B, 16B-aligned, conflict-free-ish
template<int SPLIT>
__global__ __launch_bounds__(256)
void k_sgemm(const f16* __restrict__ Ah, const f16* __restrict__ Al,
             const f16* __restrict__ Bh, const f16* __restrict__ Bl,
             float* __restrict__ C, int M, int N, int K, float alpha,
             const float* __restrict__ bias) {
    __shared__ f16 smem[(SPLIT ? 4 : 2) * 64 * LDP];
    f16* sAh = smem;
    f16* sBh = smem + 64 * LDP;
    f16* sAl = SPLIT ? smem + 2 * 64 * LDP : nullptr;
    f16* sBl = SPLIT ? smem + 3 * 64 * LDP : nullptr;

    const int tid = threadIdx.x;
    const int m0 = blockIdx.y * 64, n0 = blockIdx.x * 64;
    const int srow = tid >> 2, sk = (tid & 3) * 8;
    const int lane = tid & 63, wv = tid >> 6;
    const int wr = (wv >> 1) * 32, wc = (wv & 1) * 32;
    const int fr = lane & 15;
    const int fk = (lane >> 4) * 8;

    const f16* pA = Ah + (size_t)(m0 + srow) * K + sk;
    const f16* pB = Bh + (size_t)(n0 + srow) * K + sk;
    const f16* pAl = SPLIT ? Al + (size_t)(m0 + srow) * K + sk : nullptr;
    const f16* pBl = SPLIT ? Bl + (size_t)(n0 + srow) * K + sk : nullptr;

    f32x4 zero4 = {0.f, 0.f, 0.f, 0.f};
    f32x4 acc0[2][2] = {{zero4, zero4}, {zero4, zero4}};
    f32x4 acc1[2][2] = {{zero4, zero4}, {zero4, zero4}};

    f16x8 rA, rB, rAl, rBl;
    rA = *(const f16x8*)pA;
    rB = *(const f16x8*)pB;
    if constexpr (SPLIT) { rAl = *(const f16x8*)pAl; rBl = *(const f16x8*)pBl; }

    for (int k0 = 0; k0 < K; k0 += 32) {
        __syncthreads();
        *(f16x8*)&sAh[srow * LDP + sk] = rA;
        *(f16x8*)&sBh[srow * LDP + sk] = rB;
        if constexpr (SPLIT) {
            *(f16x8*)&sAl[srow * LDP + sk] = rAl;
            *(f16x8*)&sBl[srow * LDP + sk] = rBl;
        }
        __syncthreads();
        if (k0 + 32 < K) {
            rA = *(const f16x8*)(pA + k0 + 32);
            rB = *(const f16x8*)(pB + k0 + 32);
            if constexpr (SPLIT) {
                rAl = *(const f16x8*)(pAl + k0 + 32);
                rBl = *(const f16x8*)(pBl + k0 + 32);
            }
        }
        f16x8 ah[2], bh[2], al[2], bl[2];
        #pragma unroll
        for (int i = 0; i < 2; ++i) {
            ah[i] = *(const f16x8*)&sAh[(wr + i * 16 + fr) * LDP + fk];
            bh[i] = *(const f16x8*)&sBh[(wc + i * 16 + fr) * LDP + fk];
            if constexpr (SPLIT) {
                al[i] = *(const f16x8*)&sAl[(wr + i * 16 + fr) * LDP + fk];
                bl[i] = *(const f16x8*)&sBl[(wc + i * 16 + fr) * LDP + fk];
            }
        }
        #pragma unroll
        for (int mf = 0; mf < 2; ++mf)
            #pragma unroll
            for (int nf = 0; nf < 2; ++nf) {
                acc0[mf][nf] = __builtin_amdgcn_mfma_f32_16x16x32_f16(ah[mf], bh[nf], acc0[mf][nf], 0, 0, 0);
                if constexpr (SPLIT) {
                    acc1[mf][nf] = __builtin_amdgcn_mfma_f32_16x16x32_f16(ah[mf], bl[nf], acc1[mf][nf], 0, 0, 0);
                    acc1[mf][nf] = __builtin_amdgcn_mfma_f32_16x16x32_f16(al[mf], bh[nf], acc1[mf][nf], 0, 0, 0);
                }
            }
    }
    // epilogue: C/D layout col=lane&15, row=(lane>>4)*4+j
    #pragma unroll
    for (int mf = 0; mf < 2; ++mf)
        #pragma unroll
        for (int nf = 0; nf < 2; ++nf) {
            int orow = m0 + wr + mf * 16 + (lane >> 4) * 4;
            int ocol = n0 + wc + nf * 16 + (lane & 15);
            float bv = bias ? bias[ocol] : 0.f;
            #pragma unroll
            for (int j = 0; j < 4; ++j) {
                float v = acc0[mf][nf][j];
                if constexpr (SPLIT) v += acc1[mf][nf][j] * 9.765625e-4f;
                C[(size_t)(orow + j) * N + ocol] = alpha * v + bv;
            }
        }
}

// ---------------- cnorm + modrelu on concatenated [pr|pi] rows, + split out
__global__ __launch_bounds__(256)
void k_cnorm(float* __restrict__ p, f16* __restrict__ ph, f16* __restrict__ pl,
             const float* __restrict__ scale, const float* __restrict__ shift,
             const float* __restrict__ mbias) {
    __shared__ float red[256];
    int b = blockIdx.x, t = threadIdx.x;
    float xr[2], xi[2], hv[2];
    float lsum = 0.f;
    #pragma unroll
    for (int l = 0; l < 2; ++l) {
        int d = t + l * 256;
        float a = p[(size_t)b * ND2 + d], c = p[(size_t)b * ND2 + ND + d];
        xr[l] = a; xi[l] = c;
        float h = sqrtf(a * a + c * c);
        hv[l] = h;
        lsum += h + FEPS;
    }
    float mean = blk_sum(lsum, red) * (1.f / ND);
    float lvar = 0.f;
    #pragma unroll
    for (int l = 0; l < 2; ++l) {
        float dv = (hv[l] + FEPS) - mean;
        lvar += dv * dv;
    }
    float var = blk_sum(lvar, red) * (1.f / (ND - 1));
    float istd = 1.f / sqrtf(var + FEPS);
    #pragma unroll
    for (int l = 0; l < 2; ++l) {
        int d = t + l * 256;
        float nm = ((hv[l] + FEPS) - mean) * istd * scale[d] + shift[d];
        float cc, ss;
        if (hv[l] > 0.f) { cc = xr[l] / hv[l]; ss = xi[l] / hv[l]; }
        else             { cc = 1.f; ss = 0.f; }
        float vr_ = nm * cc, vi_ = nm * ss;
        float n = sqrtf(vr_ * vr_ + vi_ * vi_) + FEPS;
        float aarg = n + mbias[d];
        float sg = (aarg > 0.f ? aarg : 0.f) / n;
        float or_ = vr_ * sg, oi_ = vi_ * sg;
        p[(size_t)b * ND2 + d] = or_;
        p[(size_t)b * ND2 + ND + d] = oi_;
        split_write(or_, ph, pl, (size_t)b * ND2 + d);
        split_write(oi_, ph, pl, (size_t)b * ND2 + ND + d);
    }
}

// ---------------- row softmax over 1024, writes scaled (x1024) split fp16
__global__ __launch_bounds__(256)
void k_softmax(const float* __restrict__ S, f16* __restrict__ Ah, f16* __restrict__ Al) {
    __shared__ float red[256];
    int row = blockIdx.x, t = threadIdx.x;
    float v[4];
    float lm = -INFINITY;
    #pragma unroll
    for (int l = 0; l < 4; ++l) {
        v[l] = S[(size_t)row * NB + t + l * 256];
        lm = fmaxf(lm, v[l]);
    }
    float mx = blk_max(lm, red);
    float ls = 0.f;
    #pragma unroll
    for (int l = 0; l < 4; ++l) { v[l] = expf(v[l] - mx); ls += v[l]; }
    float tot = blk_sum(ls, red);
    float inv = 1024.f / tot;   // x1024 scaling keeps small weights fp16-normal
    #pragma unroll
    for (int l = 0; l < 4; ++l)
        split_write(v[l] * inv, Ah, Al, (size_t)row * NB + t + l * 256);
}

// ---------------- halt/ctrl/stack/read/cf
__global__ __launch_bounds__(256)
void k_stack(const float* __restrict__ zf, const float* __restrict__ hW,
             const float* __restrict__ hB, const float* __restrict__ cW,
             const float* __restrict__ cB, float* __restrict__ ptrb,
             float* __restrict__ memb, float* __restrict__ haltb,
             float* __restrict__ cf, f16* __restrict__ cfh, f16* __restrict__ cfl) {
    __shared__ float zfs[ND2];
    __shared__ float red[256];
    __shared__ float pt[NSTACK], npv[NSTACK], wmv[NSTACK];
    __shared__ float snorm;
    int b = blockIdx.x, t = threadIdx.x;
    for (int c = t; c < ND2; c += 256) zfs[c] = zf[(size_t)b * ND2 + c];
    __syncthreads();
    float dh = 0, d0 = 0, d1 = 0, d2 = 0;
    for (int c = t; c < ND2; c += 256) {
        float z = zfs[c];
        dh += z * hW[c];
        d0 += z * cW[c];
        d1 += z * cW[ND2 + c];
        d2 += z * cW[2 * ND2 + c];
    }
    dh = blk_sum(dh, red);
    d0 = blk_sum(d0, red);
    d1 = blk_sum(d1, red);
    d2 = blk_sum(d2, red);
    float h = 1.f / (1.f + expf(-(dh + hB[0])));
    float l0 = d0 + cB[0], l1 = d1 + cB[1], l2 = d2 + cB[2];
    float mx = fmaxf(l0, fmaxf(l1, l2));
    float e0 = expf(l0 - mx), e1 = expf(l1 - mx), e2 = expf(l2 - mx);
    float es = e0 + e1 + e2;
    float push = e0 / es, pop = e1 / es, noop = e2 / es;
    if (t < NSTACK) pt[t] = ptrb[b * NSTACK + t];
    __syncthreads();
    if (t < NSTACK) {
        float up = pt[(t + NSTACK - 1) & 15];
        float dn = pt[(t + 1) & 15];
        npv[t] = push * up + pop * dn + noop * pt[t];
        wmv[t] = push * up;
    }
    __syncthreads();
    if (t == 0) {
        float s = 0.f;
        for (int j = 0; j < NSTACK; ++j) s += npv[j];
        snorm = 1.f / (s + FEPS);
    }
    __syncthreads();
    if (t < NSTACK) {
        npv[t] *= snorm;
        ptrb[b * NSTACK + t] = npv[t];
    }
    __syncthreads();
    for (int c = t; c < ND2; c += 256) {
        float z = zfs[c];
        float rd = 0.f;
        #pragma unroll
        for (int s = 0; s < NSTACK; ++s) {
            size_t off = ((size_t)b * NSTACK + s) * ND2 + c;
            float m = memb[off];
            m = wmv[s] * z + m * (1.f - wmv[s]);
            memb[off] = m;
            rd += m * npv[s];
        }
        float v = z + rd;
        cf[(size_t)b * ND2 + c] = v;
        split_write(v, cfh, cfl, (size_t)b * ND2 + c);
    }
    if (t == 0) haltb[b] = h;
}

// ---------------- VQ argmin + losses + state update
__global__ __launch_bounds__(256)
void k_vqstep(const float* __restrict__ G, const float* __restrict__ cf,
              const float* __restrict__ cb, const float* __restrict__ cbn,
              const f16* __restrict__ cbh, const f16* __restrict__ cbl,
              const float* __restrict__ adj, const float* __restrict__ haltb,
              float* __restrict__ remainb, f16* __restrict__ zh, f16* __restrict__ zl,
              float* __restrict__ zw, int* __restrict__ prev, float* __restrict__ scal,
              int step, int islast) {
    __shared__ float sval[256];
    __shared__ int sidx[256];
    __shared__ float red[256];
    int b = blockIdx.x, t = threadIdx.x;
    float bv = INFINITY; int bi = NK;
    for (int k = t; k < NK; k += 256) {
        float v = cbn[k] - 2.f * G[(size_t)b * NK + k];
        if (v < bv) { bv = v; bi = k; }
    }
    sval[t] = bv; sidx[t] = bi;
    __syncthreads();
    for (int s = 128; s > 0; s >>= 1) {
        if (t < s) {
            float ov = sval[t + s]; int oi = sidx[t + s];
            if (ov < sval[t] || (ov == sval[t] && oi < sidx[t])) { sval[t] = ov; sidx[t] = oi; }
        }
        __syncthreads();
    }
    int sym = sidx[0];
    float sd = 0.f;
    for (int c = t; c < ND2; c += 256) {
        float dd = cb[(size_t)sym * ND2 + c] - cf[(size_t)b * ND2 + c];
        sd += dd * dd;
    }
    float sdt = blk_sum(sd, red);
    float contrib = 0.f;
    if (step > 0) {
        int pv = prev[b];
        float lm = -INFINITY;
        for (int c = t; c < NK; c += 256) lm = fmaxf(lm, adj[(size_t)pv * NK + c]);
        float mxa = blk_max(lm, red);
        float le = 0.f;
        for (int c = t; c < NK; c += 256) le += expf(adj[(size_t)pv * NK + c] - mxa);
        float se = blk_sum(le, red);
        contrib = (mxa + logf(se)) - adj[(size_t)pv * NK + sym];
    }
    float hb = haltb[b];
    float rm = remainb[b];
    float w = islast ? rm : hb * rm;
    for (int c = t; c < ND2; c += 256) {
        zw[(size_t)b * ND2 + c] += w * cb[(size_t)sym * ND2 + c];
        zh[(size_t)b * ND2 + c] = cbh[(size_t)sym * ND2 + c];
        zl[(size_t)b * ND2 + c] = cbl[(size_t)sym * ND2 + c];
    }
    if (t == 0) {
        float nrm = rm * (1.f - hb);
        remainb[b] = nrm;
        atomicAdd(&scal[0], sdt);
        if (step > 0) atomicAdd(&scal[1], contrib);
        atomicAdd(&scal[2], nrm);
        prev[b] = sym;
    }
}

__global__ void k_aux(const float* __restrict__ scal, float* __restrict__ out) {
    out[0] = 1.25f * scal[0] / (1024.f * 1024.f)
           + 0.005f * (scal[1] / 1024.f)
           + 0.0001f * (scal[2] / 1024.f);
}

// ---------------- launch ----------------
extern "C" void kernel_launch(void* const* d_in, const int* in_sizes, int n_in,
                              void* d_out, int out_size, void* d_ws, size_t ws_size,
                              hipStream_t stream) {
    const int*   input_ids  = (const int*)  d_in[0];
    const float* emb_mag    = (const float*)d_in[1];
    const float* emb_phase  = (const float*)d_in[2];
    const float* lin_r      = (const float*)d_in[3];
    const float* lin_i      = (const float*)d_in[4];
    const float* norm_scale = (const float*)d_in[5];
    const float* norm_shift = (const float*)d_in[6];
    const float* mod_bias   = (const float*)d_in[7];
    const float* halt_W     = (const float*)d_in[8];
    const float* halt_b     = (const float*)d_in[9];
    const float* ctrl_W     = (const float*)d_in[10];
    const float* ctrl_b     = (const float*)d_in[11];
    const float* q_r        = (const float*)d_in[12];
    const float* q_i        = (const float*)d_in[13];
    const float* k_r        = (const float*)d_in[14];
    const float* k_i        = (const float*)d_in[15];
    const float* v_r        = (const float*)d_in[16];
    const float* v_i        = (const float*)d_in[17];
    const float* codebook   = (const float*)d_in[18];
    const float* adjacency  = (const float*)d_in[19];
    const float* dec_W      = (const float*)d_in[20];
    const float* dec_b      = (const float*)d_in[21];
    float* out = (float*)d_out;

    // ---- workspace carve-up (f32 region, then f16 region) ----
    float* fb = (float*)d_ws;
    size_t o = 0;
    auto af = [&](size_t n) { float* p = fb + o; o += n; return p; };
    float* p      = af((size_t)NB * ND2);
    float* qkv    = af((size_t)NB * 3 * ND2);
    float* S      = af((size_t)NB * NB);      // scores; reused as VQ dot matrix G
    float* zf     = af((size_t)NB * ND2);
    float* cf     = af((size_t)NB * ND2);
    float* memb   = af((size_t)NB * NSTACK * ND2);
    float* zw     = af((size_t)NB * ND2);
    float* ptrb   = af((size_t)NB * NSTACK);
    float* haltb  = af(NB);
    float* remainb= af(NB);
    float* cbn    = af(NK);
    int*   prev   = (int*)af(NB);
    float* scal   = af(8);

    f16* hb = (f16*)(fb + o);
    size_t ho = 0;
    auto ah = [&](size_t n) { f16* q = hb + ho; ho += n; return q; };
    f16* z_h   = ah((size_t)NB * ND2);
    f16* z_l   = ah((size_t)NB * ND2);
    f16* p_h   = ah((size_t)NB * ND2);
    f16* p_l   = ah((size_t)NB * ND2);
    f16* q_h   = ah((size_t)NB * ND2);
    f16* q_l   = ah((size_t)NB * ND2);
    f16* k_h   = ah((size_t)NB * ND2);
    f16* k_l   = ah((size_t)NB * ND2);
    f16* vT_h  = ah((size_t)NB * ND2);
    f16* vT_l  = ah((size_t)NB * ND2);
    f16* A_h   = ah((size_t)NB * NB);
    f16* A_l   = ah((size_t)NB * NB);
    f16* cf_h  = ah((size_t)NB * ND2);
    f16* cf_l  = ah((size_t)NB * ND2);
    f16* zw_h  = ah((size_t)NB * ND2);
    f16* zw_l  = ah((size_t)NB * ND2);
    f16* W1_h  = ah((size_t)ND2 * ND2);
    f16* W1_l  = ah((size_t)ND2 * ND2);
    f16* Wq_h  = ah((size_t)3 * ND2 * ND2);
    f16* Wq_l  = ah((size_t)3 * ND2 * ND2);
    f16* cb_h  = ah((size_t)NK * ND2);
    f16* cb_l  = ah((size_t)NK * ND2);
    f16* dW_h  = ah((size_t)NV * ND2);

    hipMemsetAsync(memb, 0, (size_t)NB * NSTACK * ND2 * sizeof(float), stream);
    hipMemsetAsync(zw, 0, (size_t)NB * ND2 * sizeof(float), stream);
    k_init<<<4, 256, 0, stream>>>(ptrb, remainb, scal);
    k_embed<<<NB, 256, 0, stream>>>(input_ids, emb_mag, emb_phase, z_h, z_l);
    k_cbnorm<<<NK, 256, 0, stream>>>(codebook, cbn);
    k_buildW1<<<(ND2 * ND2) / 256, 256, 0, stream>>>(lin_r, lin_i, W1_h, W1_l);
    k_buildWqkv<<<(3 * ND2 * ND2) / 256, 256, 0, stream>>>(q_r, q_i, k_r, k_i, v_r, v_i, Wq_h, Wq_l);
    k_splitcb<<<(NK * ND2) / 256, 256, 0, stream>>>(codebook, cb_h, cb_l);
    k_split_h<<<2048, 256, 0, stream>>>(dec_W, dW_h, (size_t)NV * ND2);

    const float att_scale = 0.044194173824159216f;  // 1/sqrt(512)
    for (int step = 0; step < NSTEPS; ++step) {
        k_sgemm<1><<<dim3(16, 16), 256, 0, stream>>>(z_h, z_l, W1_h, W1_l, p, NB, ND2, ND2, 1.f, nullptr);
        k_cnorm<<<NB, 256, 0, stream>>>(p, p_h, p_l, norm_scale, norm_shift, mod_bias);
        k_sgemm<1><<<dim3(48, 16), 256, 0, stream>>>(p_h, p_l, Wq_h, Wq_l, qkv, NB, 3 * ND2, ND2, 1.f, nullptr);
        k_split_str<<<NB, 256, 0, stream>>>(qkv, 3 * ND2, q_h, q_l);
        k_split_str<<<NB, 256, 0, stream>>>(qkv + ND2, 3 * ND2, k_h, k_l);
        k_tsplit<<<dim3(32, 32), 256, 0, stream>>>(qkv + 2 * ND2, 3 * ND2, vT_h, vT_l);
        k_sgemm<1><<<dim3(16, 16), 256, 0, stream>>>(q_h, q_l, k_h, k_l, S, NB, NB, ND2, att_scale, nullptr);
        k_softmax<<<NB, 256, 0, stream>>>(S, A_h, A_l);
        k_sgemm<1><<<dim3(16, 16), 256, 0, stream>>>(A_h, A_l, vT_h, vT_l, zf, NB, ND2, NB, 9.765625e-4f, nullptr);
        k_stack<<<NB, 256, 0, stream>>>(zf, halt_W, halt_b, ctrl_W, ctrl_b, ptrb, memb, haltb, cf, cf_h, cf_l);
        k_sgemm<1><<<dim3(16, 16), 256, 0, stream>>>(cf_h, cf_l, cb_h, cb_l, S, NB, NK, ND2, 1.f, nullptr);
        k_vqstep<<<NB, 256, 0, stream>>>(S, cf, codebook, cbn, cb_h, cb_l, adjacency, haltb, remainb,
                                         z_h, z_l, zw, prev, scal, step, step == NSTEPS - 1 ? 1 : 0);
    }
    k_split_str<<<NB, 256, 0, stream>>>(zw, ND2, zw_h, zw_l);
    k_sgemm<0><<<dim3(NV / 64, 16), 256, 0, stream>>>(zw_h, nullptr, dW_h, nullptr, out, NB, NV, ND2, 1.f, dec_b);
    k_aux<<<1, 1, 0, stream>>>(scal, out + (size_t)NB * NV);
}

// Round 3
// 2042.075 us; speedup vs baseline: 3.7896x; 1.0745x over previous
//
#include <hip/hip_runtime.h>
#include <math.h>

#define NB 1024
#define ND 512
#define ND2 1024
#define NSTEPS 8
#define NSTACK 16
#define NK 1024
#define NV 32000
#define FEPS 1e-6f
#define SK 4           // split-K factor for per-step GEMMs

typedef _Float16 f16;
typedef f16 f16x8 __attribute__((ext_vector_type(8)));
typedef float f32x4 __attribute__((ext_vector_type(4)));

// ---------------- block reduction helpers (blockDim == 256) ----------------
__device__ __forceinline__ float blk_sum(float v, float* red) {
    int t = threadIdx.x;
    red[t] = v; __syncthreads();
    for (int s = 128; s > 0; s >>= 1) {
        if (t < s) red[t] += red[t + s];
        __syncthreads();
    }
    float r = red[0]; __syncthreads();
    return r;
}

__device__ __forceinline__ float blk_max(float v, float* red) {
    int t = threadIdx.x;
    red[t] = v; __syncthreads();
    for (int s = 128; s > 0; s >>= 1) {
        if (t < s) red[t] = fmaxf(red[t], red[t + s]);
        __syncthreads();
    }
    float r = red[0]; __syncthreads();
    return r;
}

__device__ __forceinline__ void split_write(float v, f16* oh, f16* ol, size_t idx) {
    f16 h = (f16)v;
    oh[idx] = h;
    ol[idx] = (f16)((v - (float)h) * 1024.f);
}

// ---------------- init ----------------
__global__ __launch_bounds__(256)
void k_init(float* ptrb, float* remainb, float* scal) {
    int i = blockIdx.x * 256 + threadIdx.x;
    if (i < NB) {
        remainb[i] = 1.f;
        for (int s = 0; s < NSTACK; ++s) ptrb[i * NSTACK + s] = (s == 0) ? 1.f : 0.f;
    }
    if (i < 8) scal[i] = 0.f;
}

__global__ __launch_bounds__(256)
void k_embed(const int* __restrict__ ids, const float* __restrict__ mag,
             const float* __restrict__ ph, f16* __restrict__ zh, f16* __restrict__ zl) {
    int b = blockIdx.x;
    int id = ids[b];
    for (int d = threadIdx.x; d < ND; d += 256) {
        float m = mag[(size_t)id * ND + d];
        float p = ph[(size_t)id * ND + d];
        split_write(m * cosf(p), zh, zl, (size_t)b * ND2 + d);
        split_write(m * sinf(p), zh, zl, (size_t)b * ND2 + ND + d);
    }
}

__global__ __launch_bounds__(256)
void k_cbnorm(const float* __restrict__ cb, float* __restrict__ cbn) {
    __shared__ float red[256];
    int k = blockIdx.x;
    float s = 0.f;
    for (int c = threadIdx.x; c < ND2; c += 256) {
        float v = cb[(size_t)k * ND2 + c];
        s += v * v;
    }
    float tot = blk_sum(s, red);
    if (threadIdx.x == 0) cbn[k] = tot;
}

// ---------------- weight builders ----------------
__global__ __launch_bounds__(256)
void k_buildW1(const float* __restrict__ lr, const float* __restrict__ li,
               f16* __restrict__ oh, f16* __restrict__ ol) {
    int idx = blockIdx.x * 256 + threadIdx.x;
    int n = idx >> 10, k = idx & 1023;
    float v;
    if (n < 512) v = (k < 512) ? lr[n * 512 + k] : -li[n * 512 + (k - 512)];
    else { int n2 = n - 512; v = (k < 512) ? li[n2 * 512 + k] : lr[n2 * 512 + (k - 512)]; }
    split_write(v, oh, ol, idx);
}

__global__ __launch_bounds__(256)
void k_buildWqkv(const float* __restrict__ qr, const float* __restrict__ qi,
                 const float* __restrict__ kr, const float* __restrict__ ki,
                 const float* __restrict__ vr, const float* __restrict__ vi,
                 f16* __restrict__ oh, f16* __restrict__ ol) {
    int idx = blockIdx.x * 256 + threadIdx.x;
    int n = idx >> 10, k = idx & 1023;
    int g = n >> 10, n1 = n & 1023;
    const float* Wr = (g == 0) ? qr : (g == 1) ? kr : vr;
    const float* Wi = (g == 0) ? qi : (g == 1) ? ki : vi;
    float v;
    if (n1 < 512) v = (k < 512) ? Wr[n1 * 512 + k] : -Wi[n1 * 512 + (k - 512)];
    else { int n2 = n1 - 512; v = (k < 512) ? Wi[n2 * 512 + k] : Wr[n2 * 512 + (k - 512)]; }
    split_write(v, oh, ol, idx);
}

__global__ __launch_bounds__(256)
void k_splitcb(const float* __restrict__ in, f16* __restrict__ oh, f16* __restrict__ ol) {
    int idx = blockIdx.x * 256 + threadIdx.x;
    split_write(in[idx], oh, ol, idx);
}

__global__ __launch_bounds__(256)
void k_split_h(const float* __restrict__ in, f16* __restrict__ oh, size_t n) {
    size_t i = (size_t)blockIdx.x * 256 + threadIdx.x;
    size_t st = (size_t)gridDim.x * 256;
    for (; i < n; i += st) oh[i] = (f16)in[i];
}

// sum nslab slabs of a strided M x 1024 f32 region, split into packed hi/lo fp16
__global__ __launch_bounds__(256)
void k_split_str(const float* __restrict__ in, int ld, size_t slab, int nslab,
                 f16* __restrict__ oh, f16* __restrict__ ol) {
    int b = blockIdx.x;
    for (int c = threadIdx.x; c < ND2; c += 256) {
        float v = 0.f;
        for (int s = 0; s < nslab; ++s) v += in[s * slab + (size_t)b * ld + c];
        split_write(v, oh, ol, (size_t)b * ND2 + c);
    }
}

// transpose-split with slab sum: out[n][m] = sum_s in[s][m][n]
__global__ __launch_bounds__(256)
void k_tsplit(const float* __restrict__ in, int ld, size_t slab,
              f16* __restrict__ oh, f16* __restrict__ ol) {
    __shared__ float tile[32][33];
    int bi = blockIdx.y, bj = blockIdx.x;
    int tx = threadIdx.x & 31, ty = threadIdx.x >> 5;
    for (int r = ty; r < 32; r += 8) {
        size_t off = (size_t)(bi * 32 + r) * ld + bj * 32 + tx;
        tile[r][tx] = in[off] + in[slab + off] + in[2 * slab + off] + in[3 * slab + off];
    }
    __syncthreads();
    for (int r = ty; r < 32; r += 8) {
        float v = tile[tx][r];
        split_write(v, oh, ol, (size_t)(bj * 32 + r) * ND2 + bi * 32 + tx);
    }
}

// ---------------- fp16(x2-split) MFMA NT GEMM with split-K ----------------
// Cpart[z][M,N] = alpha * (A[:, z*kc:(z+1)*kc] .* B^T slice). value = hi + lo/1024.
// Tile 64x64, BK=32, 256 threads = 4 waves (2x2), wave tile 32x32.
#define LDP 72
__global__ __launch_bounds__(256)
void k_sgemm_sk(const f16* __restrict__ Ah, const f16* __restrict__ Al,
                const f16* __restrict__ Bh, const f16* __restrict__ Bl,
                float* __restrict__ Cpart, int M, int N, int K, int kc, float alpha) {
    __shared__ f16 smem[4 * 64 * LDP];
    f16* sAh = smem;
    f16* sBh = smem + 64 * LDP;
    f16* sAl = smem + 2 * 64 * LDP;
    f16* sBl = smem + 3 * 64 * LDP;

    const int tid = threadIdx.x;
    const int m0 = blockIdx.y * 64, n0 = blockIdx.x * 64;
    const int kstart = blockIdx.z * kc;
    const int srow = tid >> 2, sk = (tid & 3) * 8;
    const int lane = tid & 63, wv = tid >> 6;
    const int wr = (wv >> 1) * 32, wc = (wv & 1) * 32;
    const int fr = lane & 15;
    const int fk = (lane >> 4) * 8;

    const f16* pA  = Ah + (size_t)(m0 + srow) * K + kstart + sk;
    const f16* pB  = Bh + (size_t)(n0 + srow) * K + kstart + sk;
    const f16* pAl = Al + (size_t)(m0 + srow) * K + kstart + sk;
    const f16* pBl = Bl + (size_t)(n0 + srow) * K + kstart + sk;

    f32x4 zero4 = {0.f, 0.f, 0.f, 0.f};
    f32x4 acc0[2][2] = {{zero4, zero4}, {zero4, zero4}};
    f32x4 acc1[2][2] = {{zero4, zero4}, {zero4, zero4}};

    f16x8 rA = *(const f16x8*)pA;
    f16x8 rB = *(const f16x8*)pB;
    f16x8 rAl = *(const f16x8*)pAl;
    f16x8 rBl = *(const f16x8*)pBl;

    for (int k0 = 0; k0 < kc; k0 += 32) {
        __syncthreads();
        *(f16x8*)&sAh[srow * LDP + sk] = rA;
        *(f16x8*)&sBh[srow * LDP + sk] = rB;
        *(f16x8*)&sAl[srow * LDP + sk] = rAl;
        *(f16x8*)&sBl[srow * LDP + sk] = rBl;
        __syncthreads();
        if (k0 + 32 < kc) {
            rA  = *(const f16x8*)(pA + k0 + 32);
            rB  = *(const f16x8*)(pB + k0 + 32);
            rAl = *(const f16x8*)(pAl + k0 + 32);
            rBl = *(const f16x8*)(pBl + k0 + 32);
        }
        f16x8 ah[2], bh[2], al[2], bl[2];
        #pragma unroll
        for (int i = 0; i < 2; ++i) {
            ah[i] = *(const f16x8*)&sAh[(wr + i * 16 + fr) * LDP + fk];
            bh[i] = *(const f16x8*)&sBh[(wc + i * 16 + fr) * LDP + fk];
            al[i] = *(const f16x8*)&sAl[(wr + i * 16 + fr) * LDP + fk];
            bl[i] = *(const f16x8*)&sBl[(wc + i * 16 + fr) * LDP + fk];
        }
        #pragma unroll
        for (int mf = 0; mf < 2; ++mf)
            #pragma unroll
            for (int nf = 0; nf < 2; ++nf) {
                acc0[mf][nf] = __builtin_amdgcn_mfma_f32_16x16x32_f16(ah[mf], bh[nf], acc0[mf][nf], 0, 0, 0);
                acc1[mf][nf] = __builtin_amdgcn_mfma_f32_16x16x32_f16(ah[mf], bl[nf], acc1[mf][nf], 0, 0, 0);
                acc1[mf][nf] = __builtin_amdgcn_mfma_f32_16x16x32_f16(al[mf], bh[nf], acc1[mf][nf], 0, 0, 0);
            }
    }
    float* C = Cpart + (size_t)blockIdx.z * M * N;
    #pragma unroll
    for (int mf = 0; mf < 2; ++mf)
        #pragma unroll
        for (int nf = 0; nf < 2; ++nf) {
            int orow = m0 + wr + mf * 16 + (lane >> 4) * 4;
            int ocol = n0 + wc + nf * 16 + (lane & 15);
            #pragma unroll
            for (int j = 0; j < 4; ++j) {
                float v = acc0[mf][nf][j] + acc1[mf][nf][j] * 9.765625e-4f;
                C[(size_t)(orow + j) * N + ocol] = alpha * v;
            }
        }
}

// ---------------- decoder GEMM: C[M,N] = A .* B^T + bias. hi-only fp16.
// BM=256, BN=128, BK=32, 512 threads = 8 waves (4M x 2N), wave tile 64x64.
#define DLDP 40
__global__ __launch_bounds__(512)
void k_dgemm(const f16* __restrict__ A, const f16* __restrict__ B,
             float* __restrict__ C, const float* __restrict__ bias,
             int M, int N, int K) {
    __shared__ f16 sA[256 * DLDP];
    __shared__ f16 sB[128 * DLDP];
    const int tid = threadIdx.x;
    const int m0 = blockIdx.x * 256, n0 = blockIdx.y * 128;
    const int lane = tid & 63, wv = tid >> 6;
    const int wr = (wv >> 1) * 64, wc = (wv & 1) * 64;
    const int fr = lane & 15, fk = (lane >> 4) * 8;
    const int ra = tid >> 1, ka = (tid & 1) * 16;
    const int rb = tid >> 2, kb = (tid & 3) * 8;

    const f16* pA = A + (size_t)(m0 + ra) * K + ka;
    const f16* pB = B + (size_t)(n0 + rb) * K + kb;

    f32x4 zero4 = {0.f, 0.f, 0.f, 0.f};
    f32x4 acc[4][4];
    #pragma unroll
    for (int i = 0; i < 4; ++i)
        #pragma unroll
        for (int j = 0; j < 4; ++j) acc[i][j] = zero4;

    f16x8 rA0 = *(const f16x8*)pA;
    f16x8 rA1 = *(const f16x8*)(pA + 8);
    f16x8 rB0 = *(const f16x8*)pB;

    for (int k0 = 0; k0 < K; k0 += 32) {
        __syncthreads();
        *(f16x8*)&sA[ra * DLDP + ka] = rA0;
        *(f16x8*)&sA[ra * DLDP + ka + 8] = rA1;
        *(f16x8*)&sB[rb * DLDP + kb] = rB0;
        __syncthreads();
        if (k0 + 32 < K) {
            rA0 = *(const f16x8*)(pA + k0 + 32);
            rA1 = *(const f16x8*)(pA + k0 + 40);
            rB0 = *(const f16x8*)(pB + k0 + 32);
        }
        f16x8 a[4], b[4];
        #pragma unroll
        for (int i = 0; i < 4; ++i) {
            a[i] = *(const f16x8*)&sA[(wr + i * 16 + fr) * DLDP + fk];
            b[i] = *(const f16x8*)&sB[(wc + i * 16 + fr) * DLDP + fk];
        }
        #pragma unroll
        for (int i = 0; i < 4; ++i)
            #pragma unroll
            for (int j = 0; j < 4; ++j)
                acc[i][j] = __builtin_amdgcn_mfma_f32_16x16x32_f16(a[i], b[j], acc[i][j], 0, 0, 0);
    }
    #pragma unroll
    for (int i = 0; i < 4; ++i)
        #pragma unroll
        for (int j = 0; j < 4; ++j) {
            int orow = m0 + wr + i * 16 + (lane >> 4) * 4;
            int ocol = n0 + wc + j * 16 + (lane & 15);
            float bv = bias[ocol];
            #pragma unroll
            for (int jj = 0; jj < 4; ++jj)
                C[(size_t)(orow + jj) * N + ocol] = acc[i][j][jj] + bv;
        }
}

// ---------------- cnorm + modrelu on summed slabs of [pr|pi] rows, split out
__global__ __launch_bounds__(256)
void k_cnorm(const float* __restrict__ p, f16* __restrict__ ph, f16* __restrict__ pl,
             const float* __restrict__ scale, const float* __restrict__ shift,
             const float* __restrict__ mbias) {
    __shared__ float red[256];
    const size_t SL = (size_t)NB * ND2;
    int b = blockIdx.x, t = threadIdx.x;
    float xr[2], xi[2], hv[2];
    float lsum = 0.f;
    #pragma unroll
    for (int l = 0; l < 2; ++l) {
        int d = t + l * 256;
        size_t o1 = (size_t)b * ND2 + d, o2 = o1 + ND;
        float a = p[o1] + p[SL + o1] + p[2 * SL + o1] + p[3 * SL + o1];
        float c = p[o2] + p[SL + o2] + p[2 * SL + o2] + p[3 * SL + o2];
        xr[l] = a; xi[l] = c;
        float h = sqrtf(a * a + c * c);
        hv[l] = h;
        lsum += h + FEPS;
    }
    float mean = blk_sum(lsum, red) * (1.f / ND);
    float lvar = 0.f;
    #pragma unroll
    for (int l = 0; l < 2; ++l) {
        float dv = (hv[l] + FEPS) - mean;
        lvar += dv * dv;
    }
    float var = blk_sum(lvar, red) * (1.f / (ND - 1));
    float istd = 1.f / sqrtf(var + FEPS);
    #pragma unroll
    for (int l = 0; l < 2; ++l) {
        int d = t + l * 256;
        float nm = ((hv[l] + FEPS) - mean) * istd * scale[d] + shift[d];
        float cc, ss;
        if (hv[l] > 0.f) { cc = xr[l] / hv[l]; ss = xi[l] / hv[l]; }
        else             { cc = 1.f; ss = 0.f; }
        float vr_ = nm * cc, vi_ = nm * ss;
        float n = sqrtf(vr_ * vr_ + vi_ * vi_) + FEPS;
        float aarg = n + mbias[d];
        float sg = (aarg > 0.f ? aarg : 0.f) / n;
        split_write(vr_ * sg, ph, pl, (size_t)b * ND2 + d);
        split_write(vi_ * sg, ph, pl, (size_t)b * ND2 + ND + d);
    }
}

// ---------------- row softmax over summed slabs, writes scaled (x1024) split fp16
__global__ __launch_bounds__(256)
void k_softmax(const float* __restrict__ S, f16* __restrict__ Ah, f16* __restrict__ Al) {
    __shared__ float red[256];
    const size_t SL = (size_t)NB * NB;
    int row = blockIdx.x, t = threadIdx.x;
    float v[4];
    float lm = -INFINITY;
    #pragma unroll
    for (int l = 0; l < 4; ++l) {
        size_t o = (size_t)row * NB + t + l * 256;
        v[l] = S[o] + S[SL + o] + S[2 * SL + o] + S[3 * SL + o];
        lm = fmaxf(lm, v[l]);
    }
    float mx = blk_max(lm, red);
    float ls = 0.f;
    #pragma unroll
    for (int l = 0; l < 4; ++l) { v[l] = expf(v[l] - mx); ls += v[l]; }
    float tot = blk_sum(ls, red);
    float inv = 1024.f / tot;
    #pragma unroll
    for (int l = 0; l < 4; ++l)
        split_write(v[l] * inv, Ah, Al, (size_t)row * NB + t + l * 256);
}

// ---------------- halt/ctrl/stack/read/cf (zf from 4 slabs)
__global__ __launch_bounds__(256)
void k_stack(const float* __restrict__ zf, const float* __restrict__ hW,
             const float* __restrict__ hB, const float* __restrict__ cW,
             const float* __restrict__ cB, float* __restrict__ ptrb,
             float* __restrict__ memb, float* __restrict__ haltb,
             float* __restrict__ cf, f16* __restrict__ cfh, f16* __restrict__ cfl) {
    __shared__ float zfs[ND2];
    __shared__ float red[256];
    __shared__ float pt[NSTACK], npv[NSTACK], wmv[NSTACK];
    __shared__ float snorm;
    const size_t SL = (size_t)NB * ND2;
    int b = blockIdx.x, t = threadIdx.x;
    for (int c = t; c < ND2; c += 256) {
        size_t o = (size_t)b * ND2 + c;
        zfs[c] = zf[o] + zf[SL + o] + zf[2 * SL + o] + zf[3 * SL + o];
    }
    __syncthreads();
    float dh = 0, d0 = 0, d1 = 0, d2 = 0;
    for (int c = t; c < ND2; c += 256) {
        float z = zfs[c];
        dh += z * hW[c];
        d0 += z * cW[c];
        d1 += z * cW[ND2 + c];
        d2 += z * cW[2 * ND2 + c];
    }
    dh = blk_sum(dh, red);
    d0 = blk_sum(d0, red);
    d1 = blk_sum(d1, red);
    d2 = blk_sum(d2, red);
    float h = 1.f / (1.f + expf(-(dh + hB[0])));
    float l0 = d0 + cB[0], l1 = d1 + cB[1], l2 = d2 + cB[2];
    float mx = fmaxf(l0, fmaxf(l1, l2));
    float e0 = expf(l0 - mx), e1 = expf(l1 - mx), e2 = expf(l2 - mx);
    float es = e0 + e1 + e2;
    float push = e0 / es, pop = e1 / es, noop = e2 / es;
    if (t < NSTACK) pt[t] = ptrb[b * NSTACK + t];
    __syncthreads();
    if (t < NSTACK) {
        float up = pt[(t + NSTACK - 1) & 15];
        float dn = pt[(t + 1) & 15];
        npv[t] = push * up + pop * dn + noop * pt[t];
        wmv[t] = push * up;
    }
    __syncthreads();
    if (t == 0) {
        float s = 0.f;
        for (int j = 0; j < NSTACK; ++j) s += npv[j];
        snorm = 1.f / (s + FEPS);
    }
    __syncthreads();
    if (t < NSTACK) {
        npv[t] *= snorm;
        ptrb[b * NSTACK + t] = npv[t];
    }
    __syncthreads();
    for (int c = t; c < ND2; c += 256) {
        float z = zfs[c];
        float rd = 0.f;
        #pragma unroll
        for (int s = 0; s < NSTACK; ++s) {
            size_t off = ((size_t)b * NSTACK + s) * ND2 + c;
            float m = memb[off];
            m = wmv[s] * z + m * (1.f - wmv[s]);
            memb[off] = m;
            rd += m * npv[s];
        }
        float v = z + rd;
        cf[(size_t)b * ND2 + c] = v;
        split_write(v, cfh, cfl, (size_t)b * ND2 + c);
    }
    if (t == 0) haltb[b] = h;
}

// ---------------- VQ argmin + losses + state update (G from 4 slabs)
__global__ __launch_bounds__(256)
void k_vqstep(const float* __restrict__ G, const float* __restrict__ cf,
              const float* __restrict__ cb, const float* __restrict__ cbn,
              const f16* __restrict__ cbh, const f16* __restrict__ cbl,
              const float* __restrict__ adj, const float* __restrict__ haltb,
              float* __restrict__ remainb, f16* __restrict__ zh, f16* __restrict__ zl,
              float* __restrict__ zw, int* __restrict__ prev, float* __restrict__ scal,
              int step, int islast) {
    __shared__ float sval[256];
    __shared__ int sidx[256];
    __shared__ float red[256];
    const size_t SL = (size_t)NB * NK;
    int b = blockIdx.x, t = threadIdx.x;
    float bv = INFINITY; int bi = NK;
    for (int k = t; k < NK; k += 256) {
        size_t o = (size_t)b * NK + k;
        float g = G[o] + G[SL + o] + G[2 * SL + o] + G[3 * SL + o];
        float v = cbn[k] - 2.f * g;
        if (v < bv) { bv = v; bi = k; }
    }
    sval[t] = bv; sidx[t] = bi;
    __syncthreads();
    for (int s = 128; s > 0; s >>= 1) {
        if (t < s) {
            float ov = sval[t + s]; int oi = sidx[t + s];
            if (ov < sval[t] || (ov == sval[t] && oi < sidx[t])) { sval[t] = ov; sidx[t] = oi; }
        }
        __syncthreads();
    }
    int sym = sidx[0];
    float sd = 0.f;
    for (int c = t; c < ND2; c += 256) {
        float dd = cb[(size_t)sym * ND2 + c] - cf[(size_t)b * ND2 + c];
        sd += dd * dd;
    }
    float sdt = blk_sum(sd, red);
    float contrib = 0.f;
    if (step > 0) {
        int pv = prev[b];
        float lm = -INFINITY;
        for (int c = t; c < NK; c += 256) lm = fmaxf(lm, adj[(size_t)pv * NK + c]);
        float mxa = blk_max(lm, red);
        float le = 0.f;
        for (int c = t; c < NK; c += 256) le += expf(adj[(size_t)pv * NK + c] - mxa);
        float se = blk_sum(le, red);
        contrib = (mxa + logf(se)) - adj[(size_t)pv * NK + sym];
    }
    float hb = haltb[b];
    float rm = remainb[b];
    float w = islast ? rm : hb * rm;
    for (int c = t; c < ND2; c += 256) {
        zw[(size_t)b * ND2 + c] += w * cb[(size_t)sym * ND2 + c];
        zh[(size_t)b * ND2 + c] = cbh[(size_t)sym * ND2 + c];
        zl[(size_t)b * ND2 + c] = cbl[(size_t)sym * ND2 + c];
    }
    if (t == 0) {
        float nrm = rm * (1.f - hb);
        remainb[b] = nrm;
        atomicAdd(&scal[0], sdt);
        if (step > 0) atomicAdd(&scal[1], contrib);
        atomicAdd(&scal[2], nrm);
        prev[b] = sym;
    }
}

__global__ void k_aux(const float* __restrict__ scal, float* __restrict__ out) {
    out[0] = 1.25f * scal[0] / (1024.f * 1024.f)
           + 0.005f * (scal[1] / 1024.f)
           + 0.0001f * (scal[2] / 1024.f);
}

// ---------------- launch ----------------
extern "C" void kernel_launch(void* const* d_in, const int* in_sizes, int n_in,
                              void* d_out, int out_size, void* d_ws, size_t ws_size,
                              hipStream_t stream) {
    const int*   input_ids  = (const int*)  d_in[0];
    const float* emb_mag    = (const float*)d_in[1];
    const float* emb_phase  = (const float*)d_in[2];
    const float* lin_r      = (const float*)d_in[3];
    const float* lin_i      = (const float*)d_in[4];
    const float* norm_scale = (const float*)d_in[5];
    const float* norm_shift = (const float*)d_in[6];
    const float* mod_bias   = (const float*)d_in[7];
    const float* halt_W     = (const float*)d_in[8];
    const float* halt_b     = (const float*)d_in[9];
    const float* ctrl_W     = (const float*)d_in[10];
    const float* ctrl_b     = (const float*)d_in[11];
    const float* q_r        = (const float*)d_in[12];
    const float* q_i        = (const float*)d_in[13];
    const float* k_r        = (const float*)d_in[14];
    const float* k_i        = (const float*)d_in[15];
    const float* v_r        = (const float*)d_in[16];
    const float* v_i        = (const float*)d_in[17];
    const float* codebook   = (const float*)d_in[18];
    const float* adjacency  = (const float*)d_in[19];
    const float* dec_W      = (const float*)d_in[20];
    const float* dec_b      = (const float*)d_in[21];
    float* out = (float*)d_out;

    // ---- workspace carve-up (f32 region, then f16 region) ----
    float* fb = (float*)d_ws;
    size_t o = 0;
    auto af = [&](size_t n) { float* p = fb + o; o += n; return p; };
    float* p_part   = af((size_t)SK * NB * ND2);      // also zf_part (aliased by time)
    float* qkv_part = af((size_t)SK * NB * 3 * ND2);
    float* S_part   = af((size_t)SK * NB * NB);       // scores; reused as VQ dot matrix G
    float* cf       = af((size_t)NB * ND2);
    float* memb     = af((size_t)NB * NSTACK * ND2);
    float* zw       = af((size_t)NB * ND2);
    float* ptrb     = af((size_t)NB * NSTACK);
    float* haltb    = af(NB);
    float* remainb  = af(NB);
    float* cbn      = af(NK);
    int*   prev     = (int*)af(NB);
    float* scal     = af(8);
    float* zf_part  = p_part;   // alias: p dead after cnorm, zf written later in step

    f16* hb = (f16*)(fb + o);
    size_t ho = 0;
    auto ah = [&](size_t n) { f16* q = hb + ho; ho += n; return q; };
    f16* z_h   = ah((size_t)NB * ND2);
    f16* z_l   = ah((size_t)NB * ND2);
    f16* p_h   = ah((size_t)NB * ND2);
    f16* p_l   = ah((size_t)NB * ND2);
    f16* q_h   = ah((size_t)NB * ND2);
    f16* q_l   = ah((size_t)NB * ND2);
    f16* k_h   = ah((size_t)NB * ND2);
    f16* k_l   = ah((size_t)NB * ND2);
    f16* vT_h  = ah((size_t)NB * ND2);
    f16* vT_l  = ah((size_t)NB * ND2);
    f16* A_h   = ah((size_t)NB * NB);
    f16* A_l   = ah((size_t)NB * NB);
    f16* cf_h  = ah((size_t)NB * ND2);
    f16* cf_l  = ah((size_t)NB * ND2);
    f16* zw_h  = ah((size_t)NB * ND2);
    f16* zw_l  = ah((size_t)NB * ND2);
    f16* W1_h  = ah((size_t)ND2 * ND2);
    f16* W1_l  = ah((size_t)ND2 * ND2);
    f16* Wq_h  = ah((size_t)3 * ND2 * ND2);
    f16* Wq_l  = ah((size_t)3 * ND2 * ND2);
    f16* cb_h  = ah((size_t)NK * ND2);
    f16* cb_l  = ah((size_t)NK * ND2);
    f16* dW_h  = ah((size_t)NV * ND2);

    hipMemsetAsync(memb, 0, (size_t)NB * NSTACK * ND2 * sizeof(float), stream);
    hipMemsetAsync(zw, 0, (size_t)NB * ND2 * sizeof(float), stream);
    k_init<<<4, 256, 0, stream>>>(ptrb, remainb, scal);
    k_embed<<<NB, 256, 0, stream>>>(input_ids, emb_mag, emb_phase, z_h, z_l);
    k_cbnorm<<<NK, 256, 0, stream>>>(codebook, cbn);
    k_buildW1<<<(ND2 * ND2) / 256, 256, 0, stream>>>(lin_r, lin_i, W1_h, W1_l);
    k_buildWqkv<<<(3 * ND2 * ND2) / 256, 256, 0, stream>>>(q_r, q_i, k_r, k_i, v_r, v_i, Wq_h, Wq_l);
    k_splitcb<<<(NK * ND2) / 256, 256, 0, stream>>>(codebook, cb_h, cb_l);
    k_split_h<<<2048, 256, 0, stream>>>(dec_W, dW_h, (size_t)NV * ND2);

    const float att_scale = 0.044194173824159216f;  // 1/sqrt(512)
    const int KC = ND2 / SK;  // 256
    const size_t qslab = (size_t)NB * 3 * ND2;
    for (int step = 0; step < NSTEPS; ++step) {
        k_sgemm_sk<<<dim3(16, 16, SK), 256, 0, stream>>>(z_h, z_l, W1_h, W1_l, p_part, NB, ND2, ND2, KC, 1.f);
        k_cnorm<<<NB, 256, 0, stream>>>(p_part, p_h, p_l, norm_scale, norm_shift, mod_bias);
        k_sgemm_sk<<<dim3(48, 16, SK), 256, 0, stream>>>(p_h, p_l, Wq_h, Wq_l, qkv_part, NB, 3 * ND2, ND2, KC, 1.f);
        k_split_str<<<NB, 256, 0, stream>>>(qkv_part, 3 * ND2, qslab, SK, q_h, q_l);
        k_split_str<<<NB, 256, 0, stream>>>(qkv_part + ND2, 3 * ND2, qslab, SK, k_h, k_l);
        k_tsplit<<<dim3(32, 32), 256, 0, stream>>>(qkv_part + 2 * ND2, 3 * ND2, qslab, vT_h, vT_l);
        k_sgemm_sk<<<dim3(16, 16, SK), 256, 0, stream>>>(q_h, q_l, k_h, k_l, S_part, NB, NB, ND2, KC, att_scale);
        k_softmax<<<NB, 256, 0, stream>>>(S_part, A_h, A_l);
        k_sgemm_sk<<<dim3(16, 16, SK), 256, 0, stream>>>(A_h, A_l, vT_h, vT_l, zf_part, NB, ND2, NB, KC, 9.765625e-4f);
        k_stack<<<NB, 256, 0, stream>>>(zf_part, halt_W, halt_b, ctrl_W, ctrl_b, ptrb, memb, haltb, cf, cf_h, cf_l);
        k_sgemm_sk<<<dim3(16, 16, SK), 256, 0, stream>>>(cf_h, cf_l, cb_h, cb_l, S_part, NB, NK, ND2, KC, 1.f);
        k_vqstep<<<NB, 256, 0, stream>>>(S_part, cf, codebook, cbn, cb_h, cb_l, adjacency, haltb, remainb,
                                         z_h, z_l, zw, prev, scal, step, step == NSTEPS - 1 ? 1 : 0);
    }
    k_split_str<<<NB, 256, 0, stream>>>(zw, ND2, 0, 1, zw_h, zw_l);
    k_dgemm<<<dim3(NB / 256, NV / 128), 512, 0, stream>>>(zw_h, dW_h, out, dec_b, NB, NV, ND2);
    k_aux<<<1, 1, 0, stream>>>(scal, out + (size_t)NB * NV);
}

// Round 4
// 1958.602 us; speedup vs baseline: 3.9511x; 1.0426x over previous
//
#include <hip/hip_runtime.h>
#include <math.h>

#define NB 1024
#define ND 512
#define ND2 1024
#define NSTEPS 8
#define NSTACK 16
#define NK 1024
#define NV 32000
#define FEPS 1e-6f

typedef _Float16 f16;
typedef f16 f16x8 __attribute__((ext_vector_type(8)));
typedef f16 f16x4 __attribute__((ext_vector_type(4)));
typedef float f32x4 __attribute__((ext_vector_type(4)));

// ---------------- block reduction helpers (blockDim == 256) ----------------
__device__ __forceinline__ float blk_sum(float v, float* red) {
    int t = threadIdx.x;
    red[t] = v; __syncthreads();
    for (int s = 128; s > 0; s >>= 1) {
        if (t < s) red[t] += red[t + s];
        __syncthreads();
    }
    float r = red[0]; __syncthreads();
    return r;
}

__device__ __forceinline__ float blk_max(float v, float* red) {
    int t = threadIdx.x;
    red[t] = v; __syncthreads();
    for (int s = 128; s > 0; s >>= 1) {
        if (t < s) red[t] = fmaxf(red[t], red[t + s]);
        __syncthreads();
    }
    float r = red[0]; __syncthreads();
    return r;
}

__device__ __forceinline__ void split_write(float v, f16* oh, f16* ol, size_t idx) {
    f16 h = (f16)v;
    oh[idx] = h;
    ol[idx] = (f16)((v - (float)h) * 1024.f);
}

// ---------------- init ----------------
__global__ __launch_bounds__(256)
void k_init(float* ptrb, float* remainb, float* scal) {
    int i = blockIdx.x * 256 + threadIdx.x;
    if (i < NB) {
        remainb[i] = 1.f;
        for (int s = 0; s < NSTACK; ++s) ptrb[i * NSTACK + s] = (s == 0) ? 1.f : 0.f;
    }
    if (i < 8) scal[i] = 0.f;
}

__global__ __launch_bounds__(256)
void k_embed(const int* __restrict__ ids, const float* __restrict__ mag,
             const float* __restrict__ ph, f16* __restrict__ zh, f16* __restrict__ zl) {
    int b = blockIdx.x;
    int id = ids[b];
    for (int d = threadIdx.x; d < ND; d += 256) {
        float m = mag[(size_t)id * ND + d];
        float p = ph[(size_t)id * ND + d];
        split_write(m * cosf(p), zh, zl, (size_t)b * ND2 + d);
        split_write(m * sinf(p), zh, zl, (size_t)b * ND2 + ND + d);
    }
}

__global__ __launch_bounds__(256)
void k_cbnorm(const float* __restrict__ cb, float* __restrict__ cbn) {
    __shared__ float red[256];
    int k = blockIdx.x;
    float s = 0.f;
    for (int c = threadIdx.x; c < ND2; c += 256) {
        float v = cb[(size_t)k * ND2 + c];
        s += v * v;
    }
    float tot = blk_sum(s, red);
    if (threadIdx.x == 0) cbn[k] = tot;
}

// ---------------- weight builders ----------------
__global__ __launch_bounds__(256)
void k_buildW1(const float* __restrict__ lr, const float* __restrict__ li,
               f16* __restrict__ oh, f16* __restrict__ ol) {
    int idx = blockIdx.x * 256 + threadIdx.x;
    int n = idx >> 10, k = idx & 1023;
    float v;
    if (n < 512) v = (k < 512) ? lr[n * 512 + k] : -li[n * 512 + (k - 512)];
    else { int n2 = n - 512; v = (k < 512) ? li[n2 * 512 + k] : lr[n2 * 512 + (k - 512)]; }
    split_write(v, oh, ol, idx);
}

__global__ __launch_bounds__(256)
void k_buildWqkv(const float* __restrict__ qr, const float* __restrict__ qi,
                 const float* __restrict__ kr, const float* __restrict__ ki,
                 const float* __restrict__ vr, const float* __restrict__ vi,
                 f16* __restrict__ oh, f16* __restrict__ ol) {
    int idx = blockIdx.x * 256 + threadIdx.x;
    int n = idx >> 10, k = idx & 1023;
    int g = n >> 10, n1 = n & 1023;
    const float* Wr = (g == 0) ? qr : (g == 1) ? kr : vr;
    const float* Wi = (g == 0) ? qi : (g == 1) ? ki : vi;
    float v;
    if (n1 < 512) v = (k < 512) ? Wr[n1 * 512 + k] : -Wi[n1 * 512 + (k - 512)];
    else { int n2 = n1 - 512; v = (k < 512) ? Wi[n2 * 512 + k] : Wr[n2 * 512 + (k - 512)]; }
    split_write(v, oh, ol, idx);
}

__global__ __launch_bounds__(256)
void k_splitcb(const float* __restrict__ in, f16* __restrict__ oh, f16* __restrict__ ol) {
    int idx = blockIdx.x * 256 + threadIdx.x;
    split_write(in[idx], oh, ol, idx);
}

__global__ __launch_bounds__(256)
void k_split_h(const float* __restrict__ in, f16* __restrict__ oh, size_t n) {
    size_t i = (size_t)blockIdx.x * 256 + threadIdx.x;
    size_t st = (size_t)gridDim.x * 256;
    for (; i < n; i += st) oh[i] = (f16)in[i];
}

__global__ __launch_bounds__(256)
void k_split1(const float* __restrict__ in, f16* __restrict__ oh, f16* __restrict__ ol) {
    int idx = blockIdx.x * 256 + threadIdx.x;
    split_write(in[idx], oh, ol, idx);
}

// ---------------- in-loop fp16(x2-split) MFMA NT GEMM, in-block split-K-2 ----
// C[M,N] = alpha * (A .* B^T). value = hi + lo/1024, 3-product compensated.
// Block: 64x64 out, 512 thr = 8 waves; group g = (tid>>8) owns K-half.
// Wave tile 32x32 (2x2 frags of 16x16x32). LDS XOR-swizzled, reg prefetch.
// EPI 0: f32 C (alpha). EPI 2: qkv fused epilogue (q/k split rows, vT transposed split).
#define LDW 40
template<int EPI>
__global__ __launch_bounds__(512)
void k_sgemm3(const f16* __restrict__ Ah, const f16* __restrict__ Al,
              const f16* __restrict__ Bh, const f16* __restrict__ Bl,
              float* __restrict__ Cf,
              f16* __restrict__ qh, f16* __restrict__ ql,
              f16* __restrict__ kh, f16* __restrict__ kl,
              f16* __restrict__ vTh, f16* __restrict__ vTl,
              int N, int K, float alpha) {
    __shared__ f16 lds[2][4][64 * LDW];   // [group][Ah,Al,Bh,Bl]
    const int tid = threadIdx.x;
    const int g = tid >> 8;
    const int gt = tid & 255;
    const int srow = gt >> 2, scb = gt & 3;
    const int sphys = ((scb ^ (srow & 3)) * 8);
    const int lane = tid & 63;
    const int q = (tid >> 6) & 3;
    const int qr = (q >> 1) * 32, qc = (q & 1) * 32;
    const int fr = lane & 15, cbk = lane >> 4;
    const int m0 = blockIdx.y * 64, n0 = blockIdx.x * 64;
    const int kbase = g * (K >> 1);
    const int iters = K >> 6;

    const f16* pA  = Ah + (size_t)(m0 + srow) * K + kbase + scb * 8;
    const f16* pAl = Al + (size_t)(m0 + srow) * K + kbase + scb * 8;
    const f16* pB  = Bh + (size_t)(n0 + srow) * K + kbase + scb * 8;
    const f16* pBl = Bl + (size_t)(n0 + srow) * K + kbase + scb * 8;

    f32x4 z4 = {0.f, 0.f, 0.f, 0.f};
    f32x4 acc0[2][2] = {{z4, z4}, {z4, z4}};
    f32x4 acc1[2][2] = {{z4, z4}, {z4, z4}};

    f16x8 rA  = *(const f16x8*)pA;
    f16x8 rAl = *(const f16x8*)pAl;
    f16x8 rB  = *(const f16x8*)pB;
    f16x8 rBl = *(const f16x8*)pBl;

    for (int it = 0; it < iters; ++it) {
        __syncthreads();
        *(f16x8*)&lds[g][0][srow * LDW + sphys] = rA;
        *(f16x8*)&lds[g][1][srow * LDW + sphys] = rAl;
        *(f16x8*)&lds[g][2][srow * LDW + sphys] = rB;
        *(f16x8*)&lds[g][3][srow * LDW + sphys] = rBl;
        __syncthreads();
        if (it + 1 < iters) {
            int ko = (it + 1) * 32;
            rA  = *(const f16x8*)(pA + ko);
            rAl = *(const f16x8*)(pAl + ko);
            rB  = *(const f16x8*)(pB + ko);
            rBl = *(const f16x8*)(pBl + ko);
        }
        f16x8 ah[2], al[2], bh[2], bl[2];
        #pragma unroll
        for (int i = 0; i < 2; ++i) {
            int ra = qr + i * 16 + fr;
            int oa = ra * LDW + ((cbk ^ (ra & 3)) * 8);
            ah[i] = *(const f16x8*)&lds[g][0][oa];
            al[i] = *(const f16x8*)&lds[g][1][oa];
            int rb = qc + i * 16 + fr;
            int ob = rb * LDW + ((cbk ^ (rb & 3)) * 8);
            bh[i] = *(const f16x8*)&lds[g][2][ob];
            bl[i] = *(const f16x8*)&lds[g][3][ob];
        }
        #pragma unroll
        for (int i = 0; i < 2; ++i)
            #pragma unroll
            for (int j = 0; j < 2; ++j) {
                acc0[i][j] = __builtin_amdgcn_mfma_f32_16x16x32_f16(ah[i], bh[j], acc0[i][j], 0, 0, 0);
                acc1[i][j] = __builtin_amdgcn_mfma_f32_16x16x32_f16(ah[i], bl[j], acc1[i][j], 0, 0, 0);
                acc1[i][j] = __builtin_amdgcn_mfma_f32_16x16x32_f16(al[i], bh[j], acc1[i][j], 0, 0, 0);
            }
    }

    float val[2][2][4];
    #pragma unroll
    for (int i = 0; i < 2; ++i)
        #pragma unroll
        for (int j = 0; j < 2; ++j)
            #pragma unroll
            for (int jj = 0; jj < 4; ++jj)
                val[i][j][jj] = acc0[i][j][jj] + acc1[i][j][jj] * 9.765625e-4f;

    __syncthreads();
    float* red = (float*)&lds[0][0][0];   // 4 waves x 32x33 f32 = 16.9 KB
    if (g == 1) {
        #pragma unroll
        for (int i = 0; i < 2; ++i)
            #pragma unroll
            for (int j = 0; j < 2; ++j) {
                int r = i * 16 + (lane >> 4) * 4, c = j * 16 + (lane & 15);
                #pragma unroll
                for (int jj = 0; jj < 4; ++jj)
                    red[q * 1056 + (r + jj) * 33 + c] = val[i][j][jj];
            }
    }
    __syncthreads();
    if (g == 0) {
        #pragma unroll
        for (int i = 0; i < 2; ++i)
            #pragma unroll
            for (int j = 0; j < 2; ++j) {
                int r = i * 16 + (lane >> 4) * 4, c = j * 16 + (lane & 15);
                #pragma unroll
                for (int jj = 0; jj < 4; ++jj)
                    val[i][j][jj] += red[q * 1056 + (r + jj) * 33 + c];
                int orow = m0 + qr + r;
                int ocol = n0 + qc + c;
                if constexpr (EPI == 0) {
                    #pragma unroll
                    for (int jj = 0; jj < 4; ++jj)
                        Cf[(size_t)(orow + jj) * N + ocol] = alpha * val[i][j][jj];
                } else {
                    int sec = ocol >> 10, lc = ocol & 1023;
                    if (sec == 0) {
                        #pragma unroll
                        for (int jj = 0; jj < 4; ++jj)
                            split_write(val[i][j][jj], qh, ql, (size_t)(orow + jj) * ND2 + lc);
                    } else if (sec == 1) {
                        #pragma unroll
                        for (int jj = 0; jj < 4; ++jj)
                            split_write(val[i][j][jj], kh, kl, (size_t)(orow + jj) * ND2 + lc);
                    } else {
                        f16x4 th, tl;
                        #pragma unroll
                        for (int jj = 0; jj < 4; ++jj) {
                            float v = val[i][j][jj];
                            f16 h = (f16)v;
                            th[jj] = h;
                            tl[jj] = (f16)((v - (float)h) * 1024.f);
                        }
                        *(f16x4*)&vTh[(size_t)lc * ND2 + orow] = th;
                        *(f16x4*)&vTl[(size_t)lc * ND2 + orow] = tl;
                    }
                }
            }
    }
}

// ---------------- decoder GEMM: C = A .* B^T + bias, hi-only fp16 ----------
// BM=BN=128, BK=32, 512 thr = 8 waves (2M x 4N), wave tile 64x32.
__global__ __launch_bounds__(512)
void k_dgemm2(const f16* __restrict__ A, const f16* __restrict__ B,
              float* __restrict__ C, const float* __restrict__ bias) {
    __shared__ f16 sA[128 * LDW];
    __shared__ f16 sB[128 * LDW];
    const int tid = threadIdx.x;
    const int srow = tid >> 2, scb = tid & 3;
    const int sphys = ((scb ^ (srow & 3)) * 8);
    const int lane = tid & 63, w = tid >> 6;
    const int wr = (w >> 2) * 64, wc = (w & 3) * 32;
    const int fr = lane & 15, cbk = lane >> 4;
    const int m0 = blockIdx.x * 128, n0 = blockIdx.y * 128;
    const int K = ND2;

    const f16* pA = A + (size_t)(m0 + srow) * K + scb * 8;
    const f16* pB = B + (size_t)(n0 + srow) * K + scb * 8;

    f32x4 z4 = {0.f, 0.f, 0.f, 0.f};
    f32x4 acc[4][2] = {{z4, z4}, {z4, z4}, {z4, z4}, {z4, z4}};
    f16x8 rA = *(const f16x8*)pA;
    f16x8 rB = *(const f16x8*)pB;

    for (int it = 0; it < 32; ++it) {
        __syncthreads();
        *(f16x8*)&sA[srow * LDW + sphys] = rA;
        *(f16x8*)&sB[srow * LDW + sphys] = rB;
        __syncthreads();
        if (it < 31) {
            int ko = (it + 1) * 32;
            rA = *(const f16x8*)(pA + ko);
            rB = *(const f16x8*)(pB + ko);
        }
        f16x8 a[4], b[2];
        #pragma unroll
        for (int i = 0; i < 4; ++i) {
            int ra = wr + i * 16 + fr;
            a[i] = *(const f16x8*)&sA[ra * LDW + ((cbk ^ (ra & 3)) * 8)];
        }
        #pragma unroll
        for (int j = 0; j < 2; ++j) {
            int rb = wc + j * 16 + fr;
            b[j] = *(const f16x8*)&sB[rb * LDW + ((cbk ^ (rb & 3)) * 8)];
        }
        #pragma unroll
        for (int i = 0; i < 4; ++i)
            #pragma unroll
            for (int j = 0; j < 2; ++j)
                acc[i][j] = __builtin_amdgcn_mfma_f32_16x16x32_f16(a[i], b[j], acc[i][j], 0, 0, 0);
    }
    #pragma unroll
    for (int i = 0; i < 4; ++i)
        #pragma unroll
        for (int j = 0; j < 2; ++j) {
            int orow = m0 + wr + i * 16 + (lane >> 4) * 4;
            int ocol = n0 + wc + j * 16 + (lane & 15);
            float bv = bias[ocol];
            #pragma unroll
            for (int jj = 0; jj < 4; ++jj)
                C[(size_t)(orow + jj) * NV + ocol] = acc[i][j][jj] + bv;
        }
}

// ---------------- cnorm + modrelu: read f32 p rows, write split fp16 -------
__global__ __launch_bounds__(256)
void k_cnorm(const float* __restrict__ p, f16* __restrict__ ph, f16* __restrict__ pl,
             const float* __restrict__ scale, const float* __restrict__ shift,
             const float* __restrict__ mbias) {
    __shared__ float red[256];
    int b = blockIdx.x, t = threadIdx.x;
    float xr[2], xi[2], hv[2];
    float lsum = 0.f;
    #pragma unroll
    for (int l = 0; l < 2; ++l) {
        int d = t + l * 256;
        float a = p[(size_t)b * ND2 + d], c = p[(size_t)b * ND2 + ND + d];
        xr[l] = a; xi[l] = c;
        float h = sqrtf(a * a + c * c);
        hv[l] = h;
        lsum += h + FEPS;
    }
    float mean = blk_sum(lsum, red) * (1.f / ND);
    float lvar = 0.f;
    #pragma unroll
    for (int l = 0; l < 2; ++l) {
        float dv = (hv[l] + FEPS) - mean;
        lvar += dv * dv;
    }
    float var = blk_sum(lvar, red) * (1.f / (ND - 1));
    float istd = 1.f / sqrtf(var + FEPS);
    #pragma unroll
    for (int l = 0; l < 2; ++l) {
        int d = t + l * 256;
        float nm = ((hv[l] + FEPS) - mean) * istd * scale[d] + shift[d];
        float cc, ss;
        if (hv[l] > 0.f) { cc = xr[l] / hv[l]; ss = xi[l] / hv[l]; }
        else             { cc = 1.f; ss = 0.f; }
        float vr_ = nm * cc, vi_ = nm * ss;
        float n = sqrtf(vr_ * vr_ + vi_ * vi_) + FEPS;
        float aarg = n + mbias[d];
        float sg = (aarg > 0.f ? aarg : 0.f) / n;
        split_write(vr_ * sg, ph, pl, (size_t)b * ND2 + d);
        split_write(vi_ * sg, ph, pl, (size_t)b * ND2 + ND + d);
    }
}

// ---------------- row softmax over 1024, writes scaled (x1024) split fp16
__global__ __launch_bounds__(256)
void k_softmax(const float* __restrict__ S, f16* __restrict__ Ah, f16* __restrict__ Al) {
    __shared__ float red[256];
    int row = blockIdx.x, t = threadIdx.x;
    float v[4];
    float lm = -INFINITY;
    #pragma unroll
    for (int l = 0; l < 4; ++l) {
        v[l] = S[(size_t)row * NB + t + l * 256];
        lm = fmaxf(lm, v[l]);
    }
    float mx = blk_max(lm, red);
    float ls = 0.f;
    #pragma unroll
    for (int l = 0; l < 4; ++l) { v[l] = expf(v[l] - mx); ls += v[l]; }
    float tot = blk_sum(ls, red);
    float inv = 1024.f / tot;
    #pragma unroll
    for (int l = 0; l < 4; ++l)
        split_write(v[l] * inv, Ah, Al, (size_t)row * NB + t + l * 256);
}

// ---------------- halt/ctrl/stack/read/cf
__global__ __launch_bounds__(256)
void k_stack(const float* __restrict__ zf, const float* __restrict__ hW,
             const float* __restrict__ hB, const float* __restrict__ cW,
             const float* __restrict__ cB, float* __restrict__ ptrb,
             float* __restrict__ memb, float* __restrict__ haltb,
             float* __restrict__ cf, f16* __restrict__ cfh, f16* __restrict__ cfl) {
    __shared__ float zfs[ND2];
    __shared__ float red[256];
    __shared__ float pt[NSTACK], npv[NSTACK], wmv[NSTACK];
    __shared__ float snorm;
    int b = blockIdx.x, t = threadIdx.x;
    for (int c = t; c < ND2; c += 256) zfs[c] = zf[(size_t)b * ND2 + c];
    __syncthreads();
    float dh = 0, d0 = 0, d1 = 0, d2 = 0;
    for (int c = t; c < ND2; c += 256) {
        float z = zfs[c];
        dh += z * hW[c];
        d0 += z * cW[c];
        d1 += z * cW[ND2 + c];
        d2 += z * cW[2 * ND2 + c];
    }
    dh = blk_sum(dh, red);
    d0 = blk_sum(d0, red);
    d1 = blk_sum(d1, red);
    d2 = blk_sum(d2, red);
    float h = 1.f / (1.f + expf(-(dh + hB[0])));
    float l0 = d0 + cB[0], l1 = d1 + cB[1], l2 = d2 + cB[2];
    float mx = fmaxf(l0, fmaxf(l1, l2));
    float e0 = expf(l0 - mx), e1 = expf(l1 - mx), e2 = expf(l2 - mx);
    float es = e0 + e1 + e2;
    float push = e0 / es, pop = e1 / es, noop = e2 / es;
    if (t < NSTACK) pt[t] = ptrb[b * NSTACK + t];
    __syncthreads();
    if (t < NSTACK) {
        float up = pt[(t + NSTACK - 1) & 15];
        float dn = pt[(t + 1) & 15];
        npv[t] = push * up + pop * dn + noop * pt[t];
        wmv[t] = push * up;
    }
    __syncthreads();
    if (t == 0) {
        float s = 0.f;
        for (int j = 0; j < NSTACK; ++j) s += npv[j];
        snorm = 1.f / (s + FEPS);
    }
    __syncthreads();
    if (t < NSTACK) {
        npv[t] *= snorm;
        ptrb[b * NSTACK + t] = npv[t];
    }
    __syncthreads();
    for (int c = t; c < ND2; c += 256) {
        float z = zfs[c];
        float rd = 0.f;
        #pragma unroll
        for (int s = 0; s < NSTACK; ++s) {
            size_t off = ((size_t)b * NSTACK + s) * ND2 + c;
            float m = memb[off];
            m = wmv[s] * z + m * (1.f - wmv[s]);
            memb[off] = m;
            rd += m * npv[s];
        }
        float v = z + rd;
        cf[(size_t)b * ND2 + c] = v;
        split_write(v, cfh, cfl, (size_t)b * ND2 + c);
    }
    if (t == 0) haltb[b] = h;
}

// ---------------- VQ argmin + losses + state update
__global__ __launch_bounds__(256)
void k_vqstep(const float* __restrict__ G, const float* __restrict__ cf,
              const float* __restrict__ cb, const float* __restrict__ cbn,
              const f16* __restrict__ cbh, const f16* __restrict__ cbl,
              const float* __restrict__ adj, const float* __restrict__ haltb,
              float* __restrict__ remainb, f16* __restrict__ zh, f16* __restrict__ zl,
              float* __restrict__ zw, int* __restrict__ prev, float* __restrict__ scal,
              int step, int islast) {
    __shared__ float sval[256];
    __shared__ int sidx[256];
    __shared__ float red[256];
    int b = blockIdx.x, t = threadIdx.x;
    float bv = INFINITY; int bi = NK;
    for (int k = t; k < NK; k += 256) {
        float v = cbn[k] - 2.f * G[(size_t)b * NK + k];
        if (v < bv) { bv = v; bi = k; }
    }
    sval[t] = bv; sidx[t] = bi;
    __syncthreads();
    for (int s = 128; s > 0; s >>= 1) {
        if (t < s) {
            float ov = sval[t + s]; int oi = sidx[t + s];
            if (ov < sval[t] || (ov == sval[t] && oi < sidx[t])) { sval[t] = ov; sidx[t] = oi; }
        }
        __syncthreads();
    }
    int sym = sidx[0];
    float sd = 0.f;
    for (int c = t; c < ND2; c += 256) {
        float dd = cb[(size_t)sym * ND2 + c] - cf[(size_t)b * ND2 + c];
        sd += dd * dd;
    }
    float sdt = blk_sum(sd, red);
    float contrib = 0.f;
    if (step > 0) {
        int pv = prev[b];
        float lm = -INFINITY;
        for (int c = t; c < NK; c += 256) lm = fmaxf(lm, adj[(size_t)pv * NK + c]);
        float mxa = blk_max(lm, red);
        float le = 0.f;
        for (int c = t; c < NK; c += 256) le += expf(adj[(size_t)pv * NK + c] - mxa);
        float se = blk_sum(le, red);
        contrib = (mxa + logf(se)) - adj[(size_t)pv * NK + sym];
    }
    float hb = haltb[b];
    float rm = remainb[b];
    float w = islast ? rm : hb * rm;
    for (int c = t; c < ND2; c += 256) {
        zw[(size_t)b * ND2 + c] += w * cb[(size_t)sym * ND2 + c];
        zh[(size_t)b * ND2 + c] = cbh[(size_t)sym * ND2 + c];
        zl[(size_t)b * ND2 + c] = cbl[(size_t)sym * ND2 + c];
    }
    if (t == 0) {
        float nrm = rm * (1.f - hb);
        remainb[b] = nrm;
        atomicAdd(&scal[0], sdt);
        if (step > 0) atomicAdd(&scal[1], contrib);
        atomicAdd(&scal[2], nrm);
        prev[b] = sym;
    }
}

__global__ void k_aux(const float* __restrict__ scal, float* __restrict__ out) {
    out[0] = 1.25f * scal[0] / (1024.f * 1024.f)
           + 0.005f * (scal[1] / 1024.f)
           + 0.0001f * (scal[2] / 1024.f);
}

// ---------------- launch ----------------
extern "C" void kernel_launch(void* const* d_in, const int* in_sizes, int n_in,
                              void* d_out, int out_size, void* d_ws, size_t ws_size,
                              hipStream_t stream) {
    const int*   input_ids  = (const int*)  d_in[0];
    const float* emb_mag    = (const float*)d_in[1];
    const float* emb_phase  = (const float*)d_in[2];
    const float* lin_r      = (const float*)d_in[3];
    const float* lin_i      = (const float*)d_in[4];
    const float* norm_scale = (const float*)d_in[5];
    const float* norm_shift = (const float*)d_in[6];
    const float* mod_bias   = (const float*)d_in[7];
    const float* halt_W     = (const float*)d_in[8];
    const float* halt_b     = (const float*)d_in[9];
    const float* ctrl_W     = (const float*)d_in[10];
    const float* ctrl_b     = (const float*)d_in[11];
    const float* q_r        = (const float*)d_in[12];
    const float* q_i        = (const float*)d_in[13];
    const float* k_r        = (const float*)d_in[14];
    const float* k_i        = (const float*)d_in[15];
    const float* v_r        = (const float*)d_in[16];
    const float* v_i        = (const float*)d_in[17];
    const float* codebook   = (const float*)d_in[18];
    const float* adjacency  = (const float*)d_in[19];
    const float* dec_W      = (const float*)d_in[20];
    const float* dec_b      = (const float*)d_in[21];
    float* out = (float*)d_out;

    // ---- workspace carve-up (f32 region, then f16 region) ----
    float* fb = (float*)d_ws;
    size_t o = 0;
    auto af = [&](size_t n) { float* p = fb + o; o += n; return p; };
    float* scr      = af((size_t)NB * ND2);   // p / S / zf / G (time-aliased)
    float* cf       = af((size_t)NB * ND2);
    float* memb     = af((size_t)NB * NSTACK * ND2);
    float* zw       = af((size_t)NB * ND2);
    float* ptrb     = af((size_t)NB * NSTACK);
    float* haltb    = af(NB);
    float* remainb  = af(NB);
    float* cbn      = af(NK);
    int*   prev     = (int*)af(NB);
    float* scal     = af(8);

    f16* hbuf = (f16*)(fb + o);
    size_t ho = 0;
    auto ah = [&](size_t n) { f16* q = hbuf + ho; ho += n; return q; };
    f16* z_h   = ah((size_t)NB * ND2);
    f16* z_l   = ah((size_t)NB * ND2);
    f16* p_h   = ah((size_t)NB * ND2);
    f16* p_l   = ah((size_t)NB * ND2);
    f16* q_h   = ah((size_t)NB * ND2);
    f16* q_l   = ah((size_t)NB * ND2);
    f16* k_h   = ah((size_t)NB * ND2);
    f16* k_l   = ah((size_t)NB * ND2);
    f16* vT_h  = ah((size_t)NB * ND2);
    f16* vT_l  = ah((size_t)NB * ND2);
    f16* A_h   = ah((size_t)NB * NB);
    f16* A_l   = ah((size_t)NB * NB);
    f16* cf_h  = ah((size_t)NB * ND2);
    f16* cf_l  = ah((size_t)NB * ND2);
    f16* zw_h  = ah((size_t)NB * ND2);
    f16* zw_l  = ah((size_t)NB * ND2);
    f16* W1_h  = ah((size_t)ND2 * ND2);
    f16* W1_l  = ah((size_t)ND2 * ND2);
    f16* Wq_h  = ah((size_t)3 * ND2 * ND2);
    f16* Wq_l  = ah((size_t)3 * ND2 * ND2);
    f16* cb_h  = ah((size_t)NK * ND2);
    f16* cb_l  = ah((size_t)NK * ND2);
    f16* dW_h  = ah((size_t)NV * ND2);

    hipMemsetAsync(memb, 0, (size_t)NB * NSTACK * ND2 * sizeof(float), stream);
    hipMemsetAsync(zw, 0, (size_t)NB * ND2 * sizeof(float), stream);
    k_init<<<4, 256, 0, stream>>>(ptrb, remainb, scal);
    k_embed<<<NB, 256, 0, stream>>>(input_ids, emb_mag, emb_phase, z_h, z_l);
    k_cbnorm<<<NK, 256, 0, stream>>>(codebook, cbn);
    k_buildW1<<<(ND2 * ND2) / 256, 256, 0, stream>>>(lin_r, lin_i, W1_h, W1_l);
    k_buildWqkv<<<(3 * ND2 * ND2) / 256, 256, 0, stream>>>(q_r, q_i, k_r, k_i, v_r, v_i, Wq_h, Wq_l);
    k_splitcb<<<(NK * ND2) / 256, 256, 0, stream>>>(codebook, cb_h, cb_l);
    k_split_h<<<2048, 256, 0, stream>>>(dec_W, dW_h, (size_t)NV * ND2);

    const float att_scale = 0.044194173824159216f;  // 1/sqrt(512)
    for (int step = 0; step < NSTEPS; ++step) {
        k_sgemm3<0><<<dim3(16, 16), 512, 0, stream>>>(z_h, z_l, W1_h, W1_l, scr,
            nullptr, nullptr, nullptr, nullptr, nullptr, nullptr, ND2, ND2, 1.f);
        k_cnorm<<<NB, 256, 0, stream>>>(scr, p_h, p_l, norm_scale, norm_shift, mod_bias);
        k_sgemm3<2><<<dim3(48, 16), 512, 0, stream>>>(p_h, p_l, Wq_h, Wq_l, nullptr,
            q_h, q_l, k_h, k_l, vT_h, vT_l, 3 * ND2, ND2, 1.f);
        k_sgemm3<0><<<dim3(16, 16), 512, 0, stream>>>(q_h, q_l, k_h, k_l, scr,
            nullptr, nullptr, nullptr, nullptr, nullptr, nullptr, NB, ND2, att_scale);
        k_softmax<<<NB, 256, 0, stream>>>(scr, A_h, A_l);
        k_sgemm3<0><<<dim3(16, 16), 512, 0, stream>>>(A_h, A_l, vT_h, vT_l, scr,
            nullptr, nullptr, nullptr, nullptr, nullptr, nullptr, ND2, NB, 9.765625e-4f);
        k_stack<<<NB, 256, 0, stream>>>(scr, halt_W, halt_b, ctrl_W, ctrl_b, ptrb, memb, haltb, cf, cf_h, cf_l);
        k_sgemm3<0><<<dim3(16, 16), 512, 0, stream>>>(cf_h, cf_l, cb_h, cb_l, scr,
            nullptr, nullptr, nullptr, nullptr, nullptr, nullptr, NK, ND2, 1.f);
        k_vqstep<<<NB, 256, 0, stream>>>(scr, cf, codebook, cbn, cb_h, cb_l, adjacency, haltb, remainb,
                                         z_h, z_l, zw, prev, scal, step, step == NSTEPS - 1 ? 1 : 0);
    }
    k_split1<<<(NB * ND2) / 256, 256, 0, stream>>>(zw, zw_h, zw_l);
    k_dgemm2<<<dim3(NB / 128, NV / 128), 512, 0, stream>>>(zw_h, dW_h, out, dec_b);
    k_aux<<<1, 1, 0, stream>>>(scal, out + (size_t)NB * NV);
}

// Round 5
// 1837.729 us; speedup vs baseline: 4.2110x; 1.0658x over previous
//
#include <hip/hip_runtime.h>
#include <math.h>

#define NB 1024
#define ND 512
#define ND2 1024
#define NSTEPS 8
#define NSTACK 16
#define NK 1024
#define NV 32000
#define FEPS 1e-6f

typedef _Float16 f16;
typedef f16 f16x8 __attribute__((ext_vector_type(8)));
typedef f16 f16x4 __attribute__((ext_vector_type(4)));
typedef float f32x4 __attribute__((ext_vector_type(4)));

// ---------------- block reduction helpers (blockDim == 256) ----------------
__device__ __forceinline__ float blk_sum(float v, float* red) {
    int t = threadIdx.x;
    red[t] = v; __syncthreads();
    for (int s = 128; s > 0; s >>= 1) {
        if (t < s) red[t] += red[t + s];
        __syncthreads();
    }
    float r = red[0]; __syncthreads();
    return r;
}

__device__ __forceinline__ float blk_max(float v, float* red) {
    int t = threadIdx.x;
    red[t] = v; __syncthreads();
    for (int s = 128; s > 0; s >>= 1) {
        if (t < s) red[t] = fmaxf(red[t], red[t + s]);
        __syncthreads();
    }
    float r = red[0]; __syncthreads();
    return r;
}

__device__ __forceinline__ void split_write(float v, f16* oh, f16* ol, size_t idx) {
    f16 h = (f16)v;
    oh[idx] = h;
    ol[idx] = (f16)((v - (float)h) * 1024.f);
}

// ---------------- init ----------------
__global__ __launch_bounds__(256)
void k_init(float* ptrb, float* remainb, float* scal) {
    int i = blockIdx.x * 256 + threadIdx.x;
    if (i < NB) {
        remainb[i] = 1.f;
        for (int s = 0; s < NSTACK; ++s) ptrb[i * NSTACK + s] = (s == 0) ? 1.f : 0.f;
    }
    if (i < 8) scal[i] = 0.f;
}

__global__ __launch_bounds__(256)
void k_embed(const int* __restrict__ ids, const float* __restrict__ mag,
             const float* __restrict__ ph, f16* __restrict__ zh, f16* __restrict__ zl) {
    int b = blockIdx.x;
    int id = ids[b];
    for (int d = threadIdx.x; d < ND; d += 256) {
        float m = mag[(size_t)id * ND + d];
        float p = ph[(size_t)id * ND + d];
        split_write(m * cosf(p), zh, zl, (size_t)b * ND2 + d);
        split_write(m * sinf(p), zh, zl, (size_t)b * ND2 + ND + d);
    }
}

__global__ __launch_bounds__(256)
void k_cbnorm(const float* __restrict__ cb, float* __restrict__ cbn) {
    __shared__ float red[256];
    int k = blockIdx.x;
    float s = 0.f;
    for (int c = threadIdx.x; c < ND2; c += 256) {
        float v = cb[(size_t)k * ND2 + c];
        s += v * v;
    }
    float tot = blk_sum(s, red);
    if (threadIdx.x == 0) cbn[k] = tot;
}

// ---------------- weight builders ----------------
__global__ __launch_bounds__(256)
void k_buildW1(const float* __restrict__ lr, const float* __restrict__ li,
               f16* __restrict__ oh, f16* __restrict__ ol) {
    int idx = blockIdx.x * 256 + threadIdx.x;
    int n = idx >> 10, k = idx & 1023;
    float v;
    if (n < 512) v = (k < 512) ? lr[n * 512 + k] : -li[n * 512 + (k - 512)];
    else { int n2 = n - 512; v = (k < 512) ? li[n2 * 512 + k] : lr[n2 * 512 + (k - 512)]; }
    split_write(v, oh, ol, idx);
}

__global__ __launch_bounds__(256)
void k_buildWqkv(const float* __restrict__ qr, const float* __restrict__ qi,
                 const float* __restrict__ kr, const float* __restrict__ ki,
                 const float* __restrict__ vr, const float* __restrict__ vi,
                 f16* __restrict__ oh, f16* __restrict__ ol) {
    int idx = blockIdx.x * 256 + threadIdx.x;
    int n = idx >> 10, k = idx & 1023;
    int g = n >> 10, n1 = n & 1023;
    const float* Wr = (g == 0) ? qr : (g == 1) ? kr : vr;
    const float* Wi = (g == 0) ? qi : (g == 1) ? ki : vi;
    float v;
    if (n1 < 512) v = (k < 512) ? Wr[n1 * 512 + k] : -Wi[n1 * 512 + (k - 512)];
    else { int n2 = n1 - 512; v = (k < 512) ? Wi[n2 * 512 + k] : Wr[n2 * 512 + (k - 512)]; }
    split_write(v, oh, ol, idx);
}

__global__ __launch_bounds__(256)
void k_splitcb(const float* __restrict__ in, f16* __restrict__ oh, f16* __restrict__ ol) {
    int idx = blockIdx.x * 256 + threadIdx.x;
    split_write(in[idx], oh, ol, idx);
}

__global__ __launch_bounds__(256)
void k_split_h(const float* __restrict__ in, f16* __restrict__ oh, size_t n) {
    size_t i = (size_t)blockIdx.x * 256 + threadIdx.x;
    size_t st = (size_t)gridDim.x * 256;
    for (; i < n; i += st) oh[i] = (f16)in[i];
}

__global__ __launch_bounds__(256)
void k_split1(const float* __restrict__ in, f16* __restrict__ oh, f16* __restrict__ ol) {
    int idx = blockIdx.x * 256 + threadIdx.x;
    split_write(in[idx], oh, ol, idx);
}

// ---------------- in-loop fp16(x2-split) MFMA NT GEMM, in-block split-K-2 ----
// C[M,N] = alpha * (A .* B^T). value = hi + lo/1024, 3-product compensated.
// Block: 64x64 out, 512 thr = 8 waves; group g = (tid>>8) owns a K-half.
// Wave tile 32x32. LDS XOR-swizzled, double-buffered (1 barrier/iter), reg prefetch.
#define LDW 40
template<int EPI>
__global__ __launch_bounds__(512, 4)
void k_sgemm3(const f16* __restrict__ Ah, const f16* __restrict__ Al,
              const f16* __restrict__ Bh, const f16* __restrict__ Bl,
              float* __restrict__ Cf,
              f16* __restrict__ qh, f16* __restrict__ ql,
              f16* __restrict__ kh, f16* __restrict__ kl,
              f16* __restrict__ vTh, f16* __restrict__ vTl,
              int N, int K, float alpha) {
    __shared__ f16 lds[2][2][4][64 * LDW];   // [buf][group][Ah,Al,Bh,Bl]
    const int tid = threadIdx.x;
    const int g = tid >> 8;
    const int gt = tid & 255;
    const int srow = gt >> 2, scb = gt & 3;
    const int sphys = ((scb ^ (srow & 3)) * 8);
    const int lane = tid & 63;
    const int q = (tid >> 6) & 3;
    const int qr = (q >> 1) * 32, qc = (q & 1) * 32;
    const int fr = lane & 15, cbk = lane >> 4;
    const int m0 = blockIdx.y * 64, n0 = blockIdx.x * 64;
    const int kbase = g * (K >> 1);
    const int iters = K >> 6;

    const f16* pA  = Ah + (size_t)(m0 + srow) * K + kbase + scb * 8;
    const f16* pAl = Al + (size_t)(m0 + srow) * K + kbase + scb * 8;
    const f16* pB  = Bh + (size_t)(n0 + srow) * K + kbase + scb * 8;
    const f16* pBl = Bl + (size_t)(n0 + srow) * K + kbase + scb * 8;

    f32x4 z4 = {0.f, 0.f, 0.f, 0.f};
    f32x4 acc0[2][2] = {{z4, z4}, {z4, z4}};
    f32x4 acc1[2][2] = {{z4, z4}, {z4, z4}};

    // prologue: stage iter0, prefetch iter1
    f16x8 rA  = *(const f16x8*)pA;
    f16x8 rAl = *(const f16x8*)pAl;
    f16x8 rB  = *(const f16x8*)pB;
    f16x8 rBl = *(const f16x8*)pBl;
    *(f16x8*)&lds[0][g][0][srow * LDW + sphys] = rA;
    *(f16x8*)&lds[0][g][1][srow * LDW + sphys] = rAl;
    *(f16x8*)&lds[0][g][2][srow * LDW + sphys] = rB;
    *(f16x8*)&lds[0][g][3][srow * LDW + sphys] = rBl;
    if (iters > 1) {
        rA  = *(const f16x8*)(pA + 32);
        rAl = *(const f16x8*)(pAl + 32);
        rB  = *(const f16x8*)(pB + 32);
        rBl = *(const f16x8*)(pBl + 32);
    }
    __syncthreads();

    for (int it = 0; it < iters; ++it) {
        const int cur = it & 1;
        f16x8 ah[2], al[2], bh[2], bl[2];
        #pragma unroll
        for (int i = 0; i < 2; ++i) {
            int ra = qr + i * 16 + fr;
            int oa = ra * LDW + ((cbk ^ (ra & 3)) * 8);
            ah[i] = *(const f16x8*)&lds[cur][g][0][oa];
            al[i] = *(const f16x8*)&lds[cur][g][1][oa];
            int rb = qc + i * 16 + fr;
            int ob = rb * LDW + ((cbk ^ (rb & 3)) * 8);
            bh[i] = *(const f16x8*)&lds[cur][g][2][ob];
            bl[i] = *(const f16x8*)&lds[cur][g][3][ob];
        }
        if (it + 1 < iters) {
            // write next tile into the other buffer (safe: everyone past barrier it-1)
            *(f16x8*)&lds[cur ^ 1][g][0][srow * LDW + sphys] = rA;
            *(f16x8*)&lds[cur ^ 1][g][1][srow * LDW + sphys] = rAl;
            *(f16x8*)&lds[cur ^ 1][g][2][srow * LDW + sphys] = rB;
            *(f16x8*)&lds[cur ^ 1][g][3][srow * LDW + sphys] = rBl;
            if (it + 2 < iters) {
                int ko = (it + 2) * 32;
                rA  = *(const f16x8*)(pA + ko);
                rAl = *(const f16x8*)(pAl + ko);
                rB  = *(const f16x8*)(pB + ko);
                rBl = *(const f16x8*)(pBl + ko);
            }
        }
        #pragma unroll
        for (int i = 0; i < 2; ++i)
            #pragma unroll
            for (int j = 0; j < 2; ++j) {
                acc0[i][j] = __builtin_amdgcn_mfma_f32_16x16x32_f16(ah[i], bh[j], acc0[i][j], 0, 0, 0);
                acc1[i][j] = __builtin_amdgcn_mfma_f32_16x16x32_f16(ah[i], bl[j], acc1[i][j], 0, 0, 0);
                acc1[i][j] = __builtin_amdgcn_mfma_f32_16x16x32_f16(al[i], bh[j], acc1[i][j], 0, 0, 0);
            }
        __syncthreads();
    }

    float val[2][2][4];
    #pragma unroll
    for (int i = 0; i < 2; ++i)
        #pragma unroll
        for (int j = 0; j < 2; ++j)
            #pragma unroll
            for (int jj = 0; jj < 4; ++jj)
                val[i][j][jj] = acc0[i][j][jj] + acc1[i][j][jj] * 9.765625e-4f;

    float* red = (float*)&lds[0][0][0][0];   // 4 waves x 32x33 f32 = 16.9 KB
    if (g == 1) {
        #pragma unroll
        for (int i = 0; i < 2; ++i)
            #pragma unroll
            for (int j = 0; j < 2; ++j) {
                int r = i * 16 + (lane >> 4) * 4, c = j * 16 + (lane & 15);
                #pragma unroll
                for (int jj = 0; jj < 4; ++jj)
                    red[q * 1056 + (r + jj) * 33 + c] = val[i][j][jj];
            }
    }
    __syncthreads();
    if (g == 0) {
        #pragma unroll
        for (int i = 0; i < 2; ++i)
            #pragma unroll
            for (int j = 0; j < 2; ++j) {
                int r = i * 16 + (lane >> 4) * 4, c = j * 16 + (lane & 15);
                #pragma unroll
                for (int jj = 0; jj < 4; ++jj)
                    val[i][j][jj] += red[q * 1056 + (r + jj) * 33 + c];
                int orow = m0 + qr + r;
                int ocol = n0 + qc + c;
                if constexpr (EPI == 0) {
                    #pragma unroll
                    for (int jj = 0; jj < 4; ++jj)
                        Cf[(size_t)(orow + jj) * N + ocol] = alpha * val[i][j][jj];
                } else {
                    int sec = ocol >> 10, lc = ocol & 1023;
                    if (sec == 0) {
                        #pragma unroll
                        for (int jj = 0; jj < 4; ++jj)
                            split_write(val[i][j][jj], qh, ql, (size_t)(orow + jj) * ND2 + lc);
                    } else if (sec == 1) {
                        #pragma unroll
                        for (int jj = 0; jj < 4; ++jj)
                            split_write(val[i][j][jj], kh, kl, (size_t)(orow + jj) * ND2 + lc);
                    } else {
                        f16x4 th, tl;
                        #pragma unroll
                        for (int jj = 0; jj < 4; ++jj) {
                            float v = val[i][j][jj];
                            f16 h = (f16)v;
                            th[jj] = h;
                            tl[jj] = (f16)((v - (float)h) * 1024.f);
                        }
                        *(f16x4*)&vTh[(size_t)lc * ND2 + orow] = th;
                        *(f16x4*)&vTl[(size_t)lc * ND2 + orow] = tl;
                    }
                }
            }
    }
}

// ---------------- decoder GEMM: C = A .* B^T + bias, hi-only fp16 ----------
// BM=256, BN=128, BK=32, 512 thr = 8 waves (4M x 2N), wave tile 64x64.
// XCD-chunked swizzle: all 4 M-blocks of a dec_W panel + ~31 consecutive
// panels land on one XCD -> B panel fetched ~once per XCD.
__global__ __launch_bounds__(512, 4)
void k_dgemm3(const f16* __restrict__ A, const f16* __restrict__ B,
              float* __restrict__ C, const float* __restrict__ bias) {
    __shared__ f16 sA[2][256 * LDW];
    __shared__ f16 sB[2][128 * LDW];
    const int bid = blockIdx.x;               // 0..999
    const int l2 = (bid & 7) * 125 + (bid >> 3);
    const int m0 = (l2 & 3) * 256;
    const int n0 = (l2 >> 2) * 128;
    const int tid = threadIdx.x;
    const int lane = tid & 63, w = tid >> 6;
    const int wr = (w >> 1) * 64, wc = (w & 1) * 64;
    const int fr = lane & 15, cbk = lane >> 4;
    const int K = ND2;
    // A staging: 256 rows x 32 halfs; thread: row=tid>>1, chunks c0=(tid&1)*2, c0+1
    const int ra = tid >> 1, ca0 = (tid & 1) * 2;
    // B staging: 128 rows x 32 halfs; thread: row=tid>>2, chunk=tid&3
    const int rb = tid >> 2, cb0 = tid & 3;

    const f16* pA = A + (size_t)(m0 + ra) * K + ca0 * 8;
    const f16* pB = B + (size_t)(n0 + rb) * K + cb0 * 8;

    f32x4 z4 = {0.f, 0.f, 0.f, 0.f};
    f32x4 acc[4][4];
    #pragma unroll
    for (int i = 0; i < 4; ++i)
        #pragma unroll
        for (int j = 0; j < 4; ++j) acc[i][j] = z4;

    f16x8 rA0 = *(const f16x8*)pA;
    f16x8 rA1 = *(const f16x8*)(pA + 8);
    f16x8 rB0 = *(const f16x8*)pB;
    sA[0][ra * LDW + (((ca0)     ^ (ra & 3)) * 8)] = 0;  // (placeholder removed by stores below)
    *(f16x8*)&sA[0][ra * LDW + (((ca0)     ^ (ra & 3)) * 8)] = rA0;
    *(f16x8*)&sA[0][ra * LDW + (((ca0 + 1) ^ (ra & 3)) * 8)] = rA1;
    *(f16x8*)&sB[0][rb * LDW + ((cb0 ^ (rb & 3)) * 8)] = rB0;
    rA0 = *(const f16x8*)(pA + 32);
    rA1 = *(const f16x8*)(pA + 40);
    rB0 = *(const f16x8*)(pB + 32);
    __syncthreads();

    for (int it = 0; it < 32; ++it) {
        const int cur = it & 1;
        f16x8 a[4], b[4];
        #pragma unroll
        for (int i = 0; i < 4; ++i) {
            int rra = wr + i * 16 + fr;
            a[i] = *(const f16x8*)&sA[cur][rra * LDW + ((cbk ^ (rra & 3)) * 8)];
        }
        #pragma unroll
        for (int j = 0; j < 4; ++j) {
            int rrb = wc + j * 16 + fr;
            b[j] = *(const f16x8*)&sB[cur][rrb * LDW + ((cbk ^ (rrb & 3)) * 8)];
        }
        if (it + 1 < 32) {
            *(f16x8*)&sA[cur ^ 1][ra * LDW + (((ca0)     ^ (ra & 3)) * 8)] = rA0;
            *(f16x8*)&sA[cur ^ 1][ra * LDW + (((ca0 + 1) ^ (ra & 3)) * 8)] = rA1;
            *(f16x8*)&sB[cur ^ 1][rb * LDW + ((cb0 ^ (rb & 3)) * 8)] = rB0;
            if (it + 2 < 32) {
                int ko = (it + 2) * 32;
                rA0 = *(const f16x8*)(pA + ko);
                rA1 = *(const f16x8*)(pA + ko + 8);
                rB0 = *(const f16x8*)(pB + ko);
            }
        }
        #pragma unroll
        for (int i = 0; i < 4; ++i)
            #pragma unroll
            for (int j = 0; j < 4; ++j)
                acc[i][j] = __builtin_amdgcn_mfma_f32_16x16x32_f16(a[i], b[j], acc[i][j], 0, 0, 0);
        __syncthreads();
    }
    #pragma unroll
    for (int i = 0; i < 4; ++i)
        #pragma unroll
        for (int j = 0; j < 4; ++j) {
            int orow = m0 + wr + i * 16 + (lane >> 4) * 4;
            int ocol = n0 + wc + j * 16 + (lane & 15);
            float bv = bias[ocol];
            #pragma unroll
            for (int jj = 0; jj < 4; ++jj)
                C[(size_t)(orow + jj) * NV + ocol] = acc[i][j][jj] + bv;
        }
}

// ---------------- cnorm + modrelu: read f32 p rows, write split fp16 -------
__global__ __launch_bounds__(256)
void k_cnorm(const float* __restrict__ p, f16* __restrict__ ph, f16* __restrict__ pl,
             const float* __restrict__ scale, const float* __restrict__ shift,
             const float* __restrict__ mbias) {
    __shared__ float red[256];
    int b = blockIdx.x, t = threadIdx.x;
    float xr[2], xi[2], hv[2];
    float lsum = 0.f;
    #pragma unroll
    for (int l = 0; l < 2; ++l) {
        int d = t + l * 256;
        float a = p[(size_t)b * ND2 + d], c = p[(size_t)b * ND2 + ND + d];
        xr[l] = a; xi[l] = c;
        float h = sqrtf(a * a + c * c);
        hv[l] = h;
        lsum += h + FEPS;
    }
    float mean = blk_sum(lsum, red) * (1.f / ND);
    float lvar = 0.f;
    #pragma unroll
    for (int l = 0; l < 2; ++l) {
        float dv = (hv[l] + FEPS) - mean;
        lvar += dv * dv;
    }
    float var = blk_sum(lvar, red) * (1.f / (ND - 1));
    float istd = 1.f / sqrtf(var + FEPS);
    #pragma unroll
    for (int l = 0; l < 2; ++l) {
        int d = t + l * 256;
        float nm = ((hv[l] + FEPS) - mean) * istd * scale[d] + shift[d];
        float cc, ss;
        if (hv[l] > 0.f) { cc = xr[l] / hv[l]; ss = xi[l] / hv[l]; }
        else             { cc = 1.f; ss = 0.f; }
        float vr_ = nm * cc, vi_ = nm * ss;
        float n = sqrtf(vr_ * vr_ + vi_ * vi_) + FEPS;
        float aarg = n + mbias[d];
        float sg = (aarg > 0.f ? aarg : 0.f) / n;
        split_write(vr_ * sg, ph, pl, (size_t)b * ND2 + d);
        split_write(vi_ * sg, ph, pl, (size_t)b * ND2 + ND + d);
    }
}

// ---------------- row softmax over 1024, writes scaled (x1024) split fp16
__global__ __launch_bounds__(256)
void k_softmax(const float* __restrict__ S, f16* __restrict__ Ah, f16* __restrict__ Al) {
    __shared__ float red[256];
    int row = blockIdx.x, t = threadIdx.x;
    float v[4];
    float lm = -INFINITY;
    #pragma unroll
    for (int l = 0; l < 4; ++l) {
        v[l] = S[(size_t)row * NB + t + l * 256];
        lm = fmaxf(lm, v[l]);
    }
    float mx = blk_max(lm, red);
    float ls = 0.f;
    #pragma unroll
    for (int l = 0; l < 4; ++l) { v[l] = expf(v[l] - mx); ls += v[l]; }
    float tot = blk_sum(ls, red);
    float inv = 1024.f / tot;
    #pragma unroll
    for (int l = 0; l < 4; ++l)
        split_write(v[l] * inv, Ah, Al, (size_t)row * NB + t + l * 256);
}

// ---------------- halt/ctrl/stack/read/cf
__global__ __launch_bounds__(256)
void k_stack(const float* __restrict__ zf, const float* __restrict__ hW,
             const float* __restrict__ hB, const float* __restrict__ cW,
             const float* __restrict__ cB, float* __restrict__ ptrb,
             float* __restrict__ memb, float* __restrict__ haltb,
             float* __restrict__ cf, f16* __restrict__ cfh, f16* __restrict__ cfl) {
    __shared__ float zfs[ND2];
    __shared__ float red[256];
    __shared__ float pt[NSTACK], npv[NSTACK], wmv[NSTACK];
    __shared__ float snorm;
    int b = blockIdx.x, t = threadIdx.x;
    for (int c = t; c < ND2; c += 256) zfs[c] = zf[(size_t)b * ND2 + c];
    __syncthreads();
    float dh = 0, d0 = 0, d1 = 0, d2 = 0;
    for (int c = t; c < ND2; c += 256) {
        float z = zfs[c];
        dh += z * hW[c];
        d0 += z * cW[c];
        d1 += z * cW[ND2 + c];
        d2 += z * cW[2 * ND2 + c];
    }
    dh = blk_sum(dh, red);
    d0 = blk_sum(d0, red);
    d1 = blk_sum(d1, red);
    d2 = blk_sum(d2, red);
    float h = 1.f / (1.f + expf(-(dh + hB[0])));
    float l0 = d0 + cB[0], l1 = d1 + cB[1], l2 = d2 + cB[2];
    float mx = fmaxf(l0, fmaxf(l1, l2));
    float e0 = expf(l0 - mx), e1 = expf(l1 - mx), e2 = expf(l2 - mx);
    float es = e0 + e1 + e2;
    float push = e0 / es, pop = e1 / es, noop = e2 / es;
    if (t < NSTACK) pt[t] = ptrb[b * NSTACK + t];
    __syncthreads();
    if (t < NSTACK) {
        float up = pt[(t + NSTACK - 1) & 15];
        float dn = pt[(t + 1) & 15];
        npv[t] = push * up + pop * dn + noop * pt[t];
        wmv[t] = push * up;
    }
    __syncthreads();
    if (t == 0) {
        float s = 0.f;
        for (int j = 0; j < NSTACK; ++j) s += npv[j];
        snorm = 1.f / (s + FEPS);
    }
    __syncthreads();
    if (t < NSTACK) {
        npv[t] *= snorm;
        ptrb[b * NSTACK + t] = npv[t];
    }
    __syncthreads();
    for (int c = t; c < ND2; c += 256) {
        float z = zfs[c];
        float rd = 0.f;
        #pragma unroll
        for (int s = 0; s < NSTACK; ++s) {
            size_t off = ((size_t)b * NSTACK + s) * ND2 + c;
            float m = memb[off];
            m = wmv[s] * z + m * (1.f - wmv[s]);
            memb[off] = m;
            rd += m * npv[s];
        }
        float v = z + rd;
        cf[(size_t)b * ND2 + c] = v;
        split_write(v, cfh, cfl, (size_t)b * ND2 + c);
    }
    if (t == 0) haltb[b] = h;
}

// ---------------- VQ argmin + losses + state update
__global__ __launch_bounds__(256)
void k_vqstep(const float* __restrict__ G, const float* __restrict__ cf,
              const float* __restrict__ cb, const float* __restrict__ cbn,
              const f16* __restrict__ cbh, const f16* __restrict__ cbl,
              const float* __restrict__ adj, const float* __restrict__ haltb,
              float* __restrict__ remainb, f16* __restrict__ zh, f16* __restrict__ zl,
              float* __restrict__ zw, int* __restrict__ prev, float* __restrict__ scal,
              int step, int islast) {
    __shared__ float sval[256];
    __shared__ int sidx[256];
    __shared__ float red[256];
    int b = blockIdx.x, t = threadIdx.x;
    float bv = INFINITY; int bi = NK;
    for (int k = t; k < NK; k += 256) {
        float v = cbn[k] - 2.f * G[(size_t)b * NK + k];
        if (v < bv) { bv = v; bi = k; }
    }
    sval[t] = bv; sidx[t] = bi;
    __syncthreads();
    for (int s = 128; s > 0; s >>= 1) {
        if (t < s) {
            float ov = sval[t + s]; int oi = sidx[t + s];
            if (ov < sval[t] || (ov == sval[t] && oi < sidx[t])) { sval[t] = ov; sidx[t] = oi; }
        }
        __syncthreads();
    }
    int sym = sidx[0];
    float sd = 0.f;
    for (int c = t; c < ND2; c += 256) {
        float dd = cb[(size_t)sym * ND2 + c] - cf[(size_t)b * ND2 + c];
        sd += dd * dd;
    }
    float sdt = blk_sum(sd, red);
    float contrib = 0.f;
    if (step > 0) {
        int pv = prev[b];
        float lm = -INFINITY;
        for (int c = t; c < NK; c += 256) lm = fmaxf(lm, adj[(size_t)pv * NK + c]);
        float mxa = blk_max(lm, red);
        float le = 0.f;
        for (int c = t; c < NK; c += 256) le += expf(adj[(size_t)pv * NK + c] - mxa);
        float se = blk_sum(le, red);
        contrib = (mxa + logf(se)) - adj[(size_t)pv * NK + sym];
    }
    float hb = haltb[b];
    float rm = remainb[b];
    float w = islast ? rm : hb * rm;
    for (int c = t; c < ND2; c += 256) {
        zw[(size_t)b * ND2 + c] += w * cb[(size_t)sym * ND2 + c];
        zh[(size_t)b * ND2 + c] = cbh[(size_t)sym * ND2 + c];
        zl[(size_t)b * ND2 + c] = cbl[(size_t)sym * ND2 + c];
    }
    if (t == 0) {
        float nrm = rm * (1.f - hb);
        remainb[b] = nrm;
        atomicAdd(&scal[0], sdt);
        if (step > 0) atomicAdd(&scal[1], contrib);
        atomicAdd(&scal[2], nrm);
        prev[b] = sym;
    }
}

__global__ void k_aux(const float* __restrict__ scal, float* __restrict__ out) {
    out[0] = 1.25f * scal[0] / (1024.f * 1024.f)
           + 0.005f * (scal[1] / 1024.f)
           + 0.0001f * (scal[2] / 1024.f);
}

// ---------------- launch ----------------
extern "C" void kernel_launch(void* const* d_in, const int* in_sizes, int n_in,
                              void* d_out, int out_size, void* d_ws, size_t ws_size,
                              hipStream_t stream) {
    const int*   input_ids  = (const int*)  d_in[0];
    const float* emb_mag    = (const float*)d_in[1];
    const float* emb_phase  = (const float*)d_in[2];
    const float* lin_r      = (const float*)d_in[3];
    const float* lin_i      = (const float*)d_in[4];
    const float* norm_scale = (const float*)d_in[5];
    const float* norm_shift = (const float*)d_in[6];
    const float* mod_bias   = (const float*)d_in[7];
    const float* halt_W     = (const float*)d_in[8];
    const float* halt_b     = (const float*)d_in[9];
    const float* ctrl_W     = (const float*)d_in[10];
    const float* ctrl_b     = (const float*)d_in[11];
    const float* q_r        = (const float*)d_in[12];
    const float* q_i        = (const float*)d_in[13];
    const float* k_r        = (const float*)d_in[14];
    const float* k_i        = (const float*)d_in[15];
    const float* v_r        = (const float*)d_in[16];
    const float* v_i        = (const float*)d_in[17];
    const float* codebook   = (const float*)d_in[18];
    const float* adjacency  = (const float*)d_in[19];
    const float* dec_W      = (const float*)d_in[20];
    const float* dec_b      = (const float*)d_in[21];
    float* out = (float*)d_out;

    // ---- workspace carve-up (f32 region, then f16 region) ----
    float* fb = (float*)d_ws;
    size_t o = 0;
    auto af = [&](size_t n) { float* p = fb + o; o += n; return p; };
    float* scr      = af((size_t)NB * ND2);   // p / S / zf / G (time-aliased)
    float* cf       = af((size_t)NB * ND2);
    float* memb     = af((size_t)NB * NSTACK * ND2);
    float* zw       = af((size_t)NB * ND2);
    float* ptrb     = af((size_t)NB * NSTACK);
    float* haltb    = af(NB);
    float* remainb  = af(NB);
    float* cbn      = af(NK);
    int*   prev     = (int*)af(NB);
    float* scal     = af(8);

    f16* hbuf = (f16*)(fb + o);
    size_t ho = 0;
    auto ah = [&](size_t n) { f16* q = hbuf + ho; ho += n; return q; };
    f16* z_h   = ah((size_t)NB * ND2);
    f16* z_l   = ah((size_t)NB * ND2);
    f16* p_h   = ah((size_t)NB * ND2);
    f16* p_l   = ah((size_t)NB * ND2);
    f16* q_h   = ah((size_t)NB * ND2);
    f16* q_l   = ah((size_t)NB * ND2);
    f16* k_h   = ah((size_t)NB * ND2);
    f16* k_l   = ah((size_t)NB * ND2);
    f16* vT_h  = ah((size_t)NB * ND2);
    f16* vT_l  = ah((size_t)NB * ND2);
    f16* A_h   = ah((size_t)NB * NB);
    f16* A_l   = ah((size_t)NB * NB);
    f16* cf_h  = ah((size_t)NB * ND2);
    f16* cf_l  = ah((size_t)NB * ND2);
    f16* zw_h  = ah((size_t)NB * ND2);
    f16* zw_l  = ah((size_t)NB * ND2);
    f16* W1_h  = ah((size_t)ND2 * ND2);
    f16* W1_l  = ah((size_t)ND2 * ND2);
    f16* Wq_h  = ah((size_t)3 * ND2 * ND2);
    f16* Wq_l  = ah((size_t)3 * ND2 * ND2);
    f16* cb_h  = ah((size_t)NK * ND2);
    f16* cb_l  = ah((size_t)NK * ND2);
    f16* dW_h  = ah((size_t)NV * ND2);

    hipMemsetAsync(memb, 0, (size_t)NB * NSTACK * ND2 * sizeof(float), stream);
    hipMemsetAsync(zw, 0, (size_t)NB * ND2 * sizeof(float), stream);
    k_init<<<4, 256, 0, stream>>>(ptrb, remainb, scal);
    k_embed<<<NB, 256, 0, stream>>>(input_ids, emb_mag, emb_phase, z_h, z_l);
    k_cbnorm<<<NK, 256, 0, stream>>>(codebook, cbn);
    k_buildW1<<<(ND2 * ND2) / 256, 256, 0, stream>>>(lin_r, lin_i, W1_h, W1_l);
    k_buildWqkv<<<(3 * ND2 * ND2) / 256, 256, 0, stream>>>(q_r, q_i, k_r, k_i, v_r, v_i, Wq_h, Wq_l);
    k_splitcb<<<(NK * ND2) / 256, 256, 0, stream>>>(codebook, cb_h, cb_l);
    k_split_h<<<2048, 256, 0, stream>>>(dec_W, dW_h, (size_t)NV * ND2);

    const float att_scale = 0.044194173824159216f;  // 1/sqrt(512)
    for (int step = 0; step < NSTEPS; ++step) {
        k_sgemm3<0><<<dim3(16, 16), 512, 0, stream>>>(z_h, z_l, W1_h, W1_l, scr,
            nullptr, nullptr, nullptr, nullptr, nullptr, nullptr, ND2, ND2, 1.f);
        k_cnorm<<<NB, 256, 0, stream>>>(scr, p_h, p_l, norm_scale, norm_shift, mod_bias);
        k_sgemm3<2><<<dim3(48, 16), 512, 0, stream>>>(p_h, p_l, Wq_h, Wq_l, nullptr,
            q_h, q_l, k_h, k_l, vT_h, vT_l, 3 * ND2, ND2, 1.f);
        k_sgemm3<0><<<dim3(16, 16), 512, 0, stream>>>(q_h, q_l, k_h, k_l, scr,
            nullptr, nullptr, nullptr, nullptr, nullptr, nullptr, NB, ND2, att_scale);
        k_softmax<<<NB, 256, 0, stream>>>(scr, A_h, A_l);
        k_sgemm3<0><<<dim3(16, 16), 512, 0, stream>>>(A_h, A_l, vT_h, vT_l, scr,
            nullptr, nullptr, nullptr, nullptr, nullptr, nullptr, ND2, NB, 9.765625e-4f);
        k_stack<<<NB, 256, 0, stream>>>(scr, halt_W, halt_b, ctrl_W, ctrl_b, ptrb, memb, haltb, cf, cf_h, cf_l);
        k_sgemm3<0><<<dim3(16, 16), 512, 0, stream>>>(cf_h, cf_l, cb_h, cb_l, scr,
            nullptr, nullptr, nullptr, nullptr, nullptr, nullptr, NK, ND2, 1.f);
        k_vqstep<<<NB, 256, 0, stream>>>(scr, cf, codebook, cbn, cb_h, cb_l, adjacency, haltb, remainb,
                                         z_h, z_l, zw, prev, scal, step, step == NSTEPS - 1 ? 1 : 0);
    }
    k_split1<<<(NB * ND2) / 256, 256, 0, stream>>>(zw, zw_h, zw_l);
    k_dgemm3<<<1000, 512, 0, stream>>>(zw_h, dW_h, out, dec_b);
    k_aux<<<1, 1, 0, stream>>>(scal, out + (size_t)NB * NV);
}